// Round 3
// baseline (374.575 us; speedup 1.0000x reference)
//
#include <hip/hip_runtime.h>

typedef unsigned short u16;
typedef __bf16 bf16_t;
typedef bf16_t bf16x8 __attribute__((ext_vector_type(8)));
typedef float f32x4 __attribute__((ext_vector_type(4)));
typedef u16 u16x8 __attribute__((ext_vector_type(8)));

__device__ __forceinline__ u16 f2bf(float f) {
  unsigned u = __float_as_uint(f);
  u += 0x7fffu + ((u >> 16) & 1u);
  return (u16)(u >> 16);
}

__device__ __forceinline__ unsigned pk2(float a, float b) {
  return (unsigned)f2bf(a) | ((unsigned)f2bf(b) << 16);
}

__device__ __forceinline__ f32x4 mfma16(bf16x8 a, bf16x8 b, f32x4 c) {
  return __builtin_amdgcn_mfma_f32_16x16x32_bf16(a, b, c, 0, 0, 0);
}

// ---------------- fp32 -> bf16 cast ----------------
__global__ __launch_bounds__(256) void castf2b(const float* __restrict__ in,
                                               u16* __restrict__ out, int n) {
  int i = blockIdx.x * 256 + threadIdx.x;
  if (i < n) out[i] = f2bf(in[i]);
}

// ---------------- GEMM: C[M][N] = A[M][K] * B[N][K]^T ----------------
__global__ __launch_bounds__(256) void gemm_bt(const u16* __restrict__ A,
                                               const u16* __restrict__ B,
                                               float* __restrict__ C,
                                               int M, int N, int K) {
  __shared__ u16 As[128][40];
  __shared__ u16 Bs[128][40];
  const int tid = threadIdx.x;
  const int lane = tid & 63;
  const int lg = lane >> 4, li = lane & 15;
  const int wave = tid >> 6;
  const int wr = (wave >> 1) * 64, wc = (wave & 1) * 64;
  const int m0 = blockIdx.y * 128, n0 = blockIdx.x * 128;
  const int lr = tid >> 1, lc = (tid & 1) * 16;

  const f32x4 fz = {0.f, 0.f, 0.f, 0.f};
  f32x4 acc[4][4];
#pragma unroll
  for (int i = 0; i < 4; i++)
#pragma unroll
    for (int j = 0; j < 4; j++) acc[i][j] = fz;

  for (int k0 = 0; k0 < K; k0 += 32) {
    const u16* ag = &A[(size_t)(m0 + lr) * K + k0 + lc];
    const u16* bg = &B[(size_t)(n0 + lr) * K + k0 + lc];
    *(u16x8*)&As[lr][lc] = *(const u16x8*)ag;
    *(u16x8*)&As[lr][lc + 8] = *(const u16x8*)(ag + 8);
    *(u16x8*)&Bs[lr][lc] = *(const u16x8*)bg;
    *(u16x8*)&Bs[lr][lc + 8] = *(const u16x8*)(bg + 8);
    __syncthreads();
    bf16x8 af[4], bfr[4];
#pragma unroll
    for (int i = 0; i < 4; i++)
      af[i] = *(const bf16x8*)&As[wr + i * 16 + li][lg * 8];
#pragma unroll
    for (int j = 0; j < 4; j++)
      bfr[j] = *(const bf16x8*)&Bs[wc + j * 16 + li][lg * 8];
#pragma unroll
    for (int i = 0; i < 4; i++)
#pragma unroll
      for (int j = 0; j < 4; j++) acc[i][j] = mfma16(af[i], bfr[j], acc[i][j]);
    __syncthreads();
  }
#pragma unroll
  for (int i = 0; i < 4; i++)
#pragma unroll
    for (int j = 0; j < 4; j++)
#pragma unroll
      for (int r = 0; r < 4; r++)
        C[(size_t)(m0 + wr + i * 16 + lg * 4 + r) * N + n0 + wc + j * 16 + li] =
            acc[i][j][r];
}

// ---------------- fused RMSNorm + RoPE + gain ----------------
__global__ __launch_bounds__(64) void rmsrope(const float* __restrict__ in, int ld,
                                              int nh, const float* __restrict__ gain,
                                              u16* __restrict__ out, int S) {
  const int row = blockIdx.x;  // b*S + s
  const int h = blockIdx.y;
  const int t = threadIdx.x;   // 0..63
  const float v = in[(size_t)row * ld + h * 64 + t];
  float ss = v * v;
#pragma unroll
  for (int m = 1; m < 64; m <<= 1) ss += __shfl_xor(ss, m);
  const float vn = v * rsqrtf(ss * (1.0f / 64.0f) + 1.1920929e-07f);
  const float partner = __shfl_xor(vn, 32);
  const int i = t & 31;
  const float inv = powf(10000.0f, -(float)(2 * i) / 64.0f);
  const int b = row / S;
  const int s = row - b * S;
  const float fr = (float)s * inv;
  float sn, cs;
  sincosf(fr, &sn, &cs);
  float o = (t < 32) ? (vn * cs + partner * sn) : (vn * cs - partner * sn);
  if (gain) o *= gain[h];
  out[((size_t)(b * nh + h) * S + s) * 64 + t] = f2bf(o);
}

// ---------------- V cast+transpose ----------------
__global__ __launch_bounds__(256) void vcast(const float* __restrict__ kvf,
                                             u16* __restrict__ vt, int S) {
  int idx = blockIdx.x * 256 + threadIdx.x;
  int row = idx >> 8;
  int c = idx & 255;
  int b = row / S, s = row - b * S;
  int kv = c >> 6, d = c & 63;
  vt[((size_t)(b * 4 + kv) * 64 + d) * S + s] = f2bf(kvf[(size_t)row * 512 + 256 + c]);
}

// ---------------- flash attention v3: register-pipelined ----------------
// qh: [B][16][S][64], kh: [B][4][S][64], vt: [B][4][64][S], y: [B*S][1024]
__global__ __launch_bounds__(256, 2) void attn3(const u16* __restrict__ qh,
                                                const u16* __restrict__ kh,
                                                const u16* __restrict__ vt,
                                                u16* __restrict__ y, int S) {
  const int nqb = S >> 6;
  const int qb = (nqb - 1) - (blockIdx.x % nqb);  // heavy tiles first
  const int bh = blockIdx.x / nqb;
  const int h = bh & 15, b = bh >> 4;
  const int kvh = h >> 2;
  const int tid = threadIdx.x;
  const int wave = tid >> 6;
  const int lane = tid & 63;
  const int lg = lane >> 4, li = lane & 15;
  const int q0 = qb * 64 + wave * 16;  // this wave's 16 q rows
  const int qrow = q0 + li;

  const u16* qp = qh + ((size_t)(b * 16 + h) * S + q0) * 64;
  const u16* kp = kh + (size_t)(b * 4 + kvh) * S * 64;
  const u16* vp = vt + (size_t)(b * 4 + kvh) * 64 * S;

  // Q as B-operand: col = q row (li), k = lg*8+j
  const bf16x8 qf0 = *(const bf16x8*)&qp[li * 64 + lg * 8];
  const bf16x8 qf1 = *(const bf16x8*)&qp[li * 64 + 32 + lg * 8];

  // per-wave P buffer: 16 rows x 64 keys bf16, stride 72 u16 (144B, 16B-aligned)
  __shared__ __align__(16) u16 Ps[4][16][72];
  char* psrow = (char*)&Ps[wave][li][0];
  const int swz = li & 7;

  const f32x4 fz = {0.f, 0.f, 0.f, 0.f};
  f32x4 o[4];
#pragma unroll
  for (int j = 0; j < 4; j++) o[j] = fz;
  float mrow = -1e30f, lrow = 0.f;

  // prefetch K tile 0 into registers
  bf16x8 kc[8];
#pragma unroll
  for (int t = 0; t < 4; t++) {
    const u16* kr = &kp[(size_t)(t * 16 + li) * 64 + lg * 8];
    kc[2 * t] = *(const bf16x8*)kr;
    kc[2 * t + 1] = *(const bf16x8*)(kr + 32);
  }

  const int kbend = q0 + 15;
  for (int kb = 0; kb <= kbend; kb += 64) {
    // V loads for current tile (consumed after softmax -> latency hidden)
    bf16x8 vcur[8];
#pragma unroll
    for (int j = 0; j < 4; j++) {
      const u16* vr = &vp[(size_t)(j * 16 + li) * S + kb + lg * 8];
      vcur[2 * j] = *(const bf16x8*)vr;
      vcur[2 * j + 1] = *(const bf16x8*)(vr + 32);
    }
    // prefetch next K tile (consumed next iteration)
    const int kbn = (kb + 64 <= kbend) ? kb + 64 : kb;
    bf16x8 knx[8];
#pragma unroll
    for (int t = 0; t < 4; t++) {
      const u16* kr = &kp[(size_t)(kbn + t * 16 + li) * 64 + lg * 8];
      knx[2 * t] = *(const bf16x8*)kr;
      knx[2 * t + 1] = *(const bf16x8*)(kr + 32);
    }
    // --- S^T = K · Q^T from registers ---
    f32x4 s[4];
#pragma unroll
    for (int t = 0; t < 4; t++) {
      s[t] = mfma16(kc[2 * t], qf0, fz);
      s[t] = mfma16(kc[2 * t + 1], qf1, s[t]);
    }
    // --- mask + scale; per-lane: 16 keys of one q row ---
    float pv[16];
#pragma unroll
    for (int t = 0; t < 4; t++)
#pragma unroll
      for (int r = 0; r < 4; r++) {
        float x = s[t][r] * 0.125f;
        pv[t * 4 + r] = (kb + t * 16 + lg * 4 + r > qrow) ? -1e30f : x;
      }
    // --- online softmax ---
    float mt = pv[0];
#pragma unroll
    for (int i = 1; i < 16; i++) mt = fmaxf(mt, pv[i]);
    mt = fmaxf(mt, __shfl_xor(mt, 16));
    mt = fmaxf(mt, __shfl_xor(mt, 32));
    const float mnew = fmaxf(mrow, mt);
    const float corr = __expf(mrow - mnew);
    mrow = mnew;
    float psum = 0.f;
#pragma unroll
    for (int i = 0; i < 16; i++) {
      pv[i] = __expf(pv[i] - mnew);
      psum += pv[i];
    }
    psum += __shfl_xor(psum, 16);
    psum += __shfl_xor(psum, 32);
    lrow = lrow * corr + psum;
    // --- P -> LDS (bf16, swizzled) ---
#pragma unroll
    for (int t = 0; t < 4; t++) {
      uint2 w;
      w.x = pk2(pv[t * 4 + 0], pv[t * 4 + 1]);
      w.y = pk2(pv[t * 4 + 2], pv[t * 4 + 3]);
      const int c8 = (t * 4 + lg) ^ (swz << 1);
      *(uint2*)(psrow + c8 * 8) = w;
    }
    // --- rescale O by corr ---
#pragma unroll
    for (int r = 0; r < 4; r++) {
      const float cb = __shfl(corr, lg * 4 + r);
      o[0][r] *= cb; o[1][r] *= cb; o[2][r] *= cb; o[3][r] *= cb;
    }
    // --- PV ---
    const bf16x8 pa0 = *(const bf16x8*)(psrow + ((lg + 0) ^ swz) * 16);
    const bf16x8 pa1 = *(const bf16x8*)(psrow + ((lg + 4) ^ swz) * 16);
#pragma unroll
    for (int j = 0; j < 4; j++) {
      o[j] = mfma16(pa0, vcur[2 * j], o[j]);
      o[j] = mfma16(pa1, vcur[2 * j + 1], o[j]);
    }
    // rotate prefetched K into place
#pragma unroll
    for (int i = 0; i < 8; i++) kc[i] = knx[i];
  }
  // --- epilogue ---
  float linv[4];
#pragma unroll
  for (int r = 0; r < 4; r++) linv[r] = 1.0f / __shfl(lrow, lg * 4 + r);
#pragma unroll
  for (int j = 0; j < 4; j++)
#pragma unroll
    for (int r = 0; r < 4; r++)
      y[((size_t)(b * S + q0 + lg * 4 + r)) * 1024 + h * 64 + j * 16 + li] =
          f2bf(o[j][r] * linv[r]);
}

extern "C" void kernel_launch(void* const* d_in, const int* in_sizes, int n_in,
                              void* d_out, int out_size, void* d_ws, size_t ws_size,
                              hipStream_t stream) {
  const float* x  = (const float*)d_in[0];
  const float* Wq = (const float*)d_in[1];
  const float* Wk = (const float*)d_in[2];
  const float* Wv = (const float*)d_in[3];
  const float* Wp = (const float*)d_in[4];
  const float* qg = (const float*)d_in[5];
  float* out = (float*)d_out;

  const int S = 2048;
  char* ws = (char*)d_ws;
  u16*   xb   = (u16*)(ws + 0);
  u16*   wqb  = (u16*)(ws + 8388608);
  u16*   wkvb = (u16*)(ws + 10485760);
  u16*   wpb  = (u16*)(ws + 11534336);
  float* qf   = (float*)(ws + 13631488);
  float* kvf  = (float*)(ws + 30408704);
  u16*   qhb  = (u16*)(ws + 38797312);
  u16*   khb  = (u16*)(ws + 47185920);
  u16*   vtb  = (u16*)(ws + 49283072);
  u16*   yb   = (u16*)(ws + 51380224);
  if (ws_size < 59768832) return;

  castf2b<<<16384, 256, 0, stream>>>(x, xb, 4194304);
  castf2b<<<4096, 256, 0, stream>>>(Wq, wqb, 1048576);
  castf2b<<<1024, 256, 0, stream>>>(Wk, wkvb, 262144);
  castf2b<<<1024, 256, 0, stream>>>(Wv, wkvb + 262144, 262144);
  castf2b<<<4096, 256, 0, stream>>>(Wp, wpb, 1048576);

  gemm_bt<<<dim3(8, 32), 256, 0, stream>>>(xb, wqb, qf, 4096, 1024, 1024);
  gemm_bt<<<dim3(4, 32), 256, 0, stream>>>(xb, wkvb, kvf, 4096, 512, 1024);

  rmsrope<<<dim3(4096, 16), 64, 0, stream>>>(qf, 1024, 16, qg, qhb, S);
  rmsrope<<<dim3(4096, 4), 64, 0, stream>>>(kvf, 512, 4, nullptr, khb, S);
  vcast<<<4096, 256, 0, stream>>>(kvf, vtb, S);

  attn3<<<1024, 256, 0, stream>>>(qhb, khb, vtb, yb, S);

  gemm_bt<<<dim3(8, 32), 256, 0, stream>>>(yb, wpb, out, 4096, 1024, 1024);
}

// Round 4
// 207.244 us; speedup vs baseline: 1.8074x; 1.8074x over previous
//
#include <hip/hip_runtime.h>

typedef unsigned short u16;
typedef __bf16 bf16_t;
typedef bf16_t bf16x8 __attribute__((ext_vector_type(8)));
typedef float f32x4 __attribute__((ext_vector_type(4)));
typedef u16 u16x8 __attribute__((ext_vector_type(8)));

__device__ __forceinline__ u16 f2bf(float f) {
  unsigned u = __float_as_uint(f);
  u += 0x7fffu + ((u >> 16) & 1u);
  return (u16)(u >> 16);
}

__device__ __forceinline__ unsigned pk2(float a, float b) {
  return (unsigned)f2bf(a) | ((unsigned)f2bf(b) << 16);
}

__device__ __forceinline__ f32x4 mfma16(bf16x8 a, bf16x8 b, f32x4 c) {
  return __builtin_amdgcn_mfma_f32_16x16x32_bf16(a, b, c, 0, 0, 0);
}

// async global->LDS, 16B per lane; LDS dest is wave-uniform base + lane*16
__device__ __forceinline__ void gl2lds16(const u16* g, u16* l) {
  __builtin_amdgcn_global_load_lds(
      (__attribute__((address_space(1))) void*)(u16*)g,
      (__attribute__((address_space(3))) void*)l, 16, 0, 0);
}

// ---------------- fp32 -> bf16 cast ----------------
__global__ __launch_bounds__(256) void castf2b(const float* __restrict__ in,
                                               u16* __restrict__ out, int n) {
  int i = blockIdx.x * 256 + threadIdx.x;
  if (i < n) out[i] = f2bf(in[i]);
}

// ---------------- GEMM: C[M][N] = A[M][K] * B[N][K]^T ----------------
__global__ __launch_bounds__(256) void gemm_bt(const u16* __restrict__ A,
                                               const u16* __restrict__ B,
                                               float* __restrict__ C,
                                               int M, int N, int K) {
  __shared__ u16 As[128][40];
  __shared__ u16 Bs[128][40];
  const int tid = threadIdx.x;
  const int lane = tid & 63;
  const int lg = lane >> 4, li = lane & 15;
  const int wave = tid >> 6;
  const int wr = (wave >> 1) * 64, wc = (wave & 1) * 64;
  const int m0 = blockIdx.y * 128, n0 = blockIdx.x * 128;
  const int lr = tid >> 1, lc = (tid & 1) * 16;

  const f32x4 fz = {0.f, 0.f, 0.f, 0.f};
  f32x4 acc[4][4];
#pragma unroll
  for (int i = 0; i < 4; i++)
#pragma unroll
    for (int j = 0; j < 4; j++) acc[i][j] = fz;

  for (int k0 = 0; k0 < K; k0 += 32) {
    const u16* ag = &A[(size_t)(m0 + lr) * K + k0 + lc];
    const u16* bg = &B[(size_t)(n0 + lr) * K + k0 + lc];
    *(u16x8*)&As[lr][lc] = *(const u16x8*)ag;
    *(u16x8*)&As[lr][lc + 8] = *(const u16x8*)(ag + 8);
    *(u16x8*)&Bs[lr][lc] = *(const u16x8*)bg;
    *(u16x8*)&Bs[lr][lc + 8] = *(const u16x8*)(bg + 8);
    __syncthreads();
    bf16x8 af[4], bfr[4];
#pragma unroll
    for (int i = 0; i < 4; i++)
      af[i] = *(const bf16x8*)&As[wr + i * 16 + li][lg * 8];
#pragma unroll
    for (int j = 0; j < 4; j++)
      bfr[j] = *(const bf16x8*)&Bs[wc + j * 16 + li][lg * 8];
#pragma unroll
    for (int i = 0; i < 4; i++)
#pragma unroll
      for (int j = 0; j < 4; j++) acc[i][j] = mfma16(af[i], bfr[j], acc[i][j]);
    __syncthreads();
  }
#pragma unroll
  for (int i = 0; i < 4; i++)
#pragma unroll
    for (int j = 0; j < 4; j++)
#pragma unroll
      for (int r = 0; r < 4; r++)
        C[(size_t)(m0 + wr + i * 16 + lg * 4 + r) * N + n0 + wc + j * 16 + li] =
            acc[i][j][r];
}

// ---------------- fused RMSNorm + RoPE + gain ----------------
__global__ __launch_bounds__(64) void rmsrope(const float* __restrict__ in, int ld,
                                              int nh, const float* __restrict__ gain,
                                              u16* __restrict__ out, int S) {
  const int row = blockIdx.x;
  const int h = blockIdx.y;
  const int t = threadIdx.x;
  const float v = in[(size_t)row * ld + h * 64 + t];
  float ss = v * v;
#pragma unroll
  for (int m = 1; m < 64; m <<= 1) ss += __shfl_xor(ss, m);
  const float vn = v * rsqrtf(ss * (1.0f / 64.0f) + 1.1920929e-07f);
  const float partner = __shfl_xor(vn, 32);
  const int i = t & 31;
  const float inv = powf(10000.0f, -(float)(2 * i) / 64.0f);
  const int b = row / S;
  const int s = row - b * S;
  const float fr = (float)s * inv;
  float sn, cs;
  sincosf(fr, &sn, &cs);
  float o = (t < 32) ? (vn * cs + partner * sn) : (vn * cs - partner * sn);
  if (gain) o *= gain[h];
  out[((size_t)(b * nh + h) * S + s) * 64 + t] = f2bf(o);
}

// ---------------- V cast+transpose ----------------
__global__ __launch_bounds__(256) void vcast(const float* __restrict__ kvf,
                                             u16* __restrict__ vt, int S) {
  int idx = blockIdx.x * 256 + threadIdx.x;
  int row = idx >> 8;
  int c = idx & 255;
  int b = row / S, s = row - b * S;
  int kv = c >> 6, d = c & 63;
  vt[((size_t)(b * 4 + kv) * 64 + d) * S + s] = f2bf(kvf[(size_t)row * 512 + 256 + c]);
}

// ---------------- flash attention v4: LDS-staged K/V, dbuf + counted vmcnt --
// qh: [B][16][S][64], kh: [B][4][S][64], vt: [B][4][64][S], y: [B*S][1024]
// grid = 32 * (S/64); bh = blockIdx & 31, qb = blockIdx >> 5 (CU load balance)
__global__ __launch_bounds__(256) void attn4(const u16* __restrict__ qh,
                                             const u16* __restrict__ kh,
                                             const u16* __restrict__ vt,
                                             u16* __restrict__ y, int S) {
  const int bh = blockIdx.x & 31;
  const int qb = blockIdx.x >> 5;
  const int h = bh & 15, b = bh >> 4;
  const int kvh = h >> 2;
  const int tid = threadIdx.x;
  const int wave = tid >> 6;
  const int lane = tid & 63;
  const int lg = lane >> 4, li = lane & 15;
  const int q0 = qb * 64 + wave * 16;
  const int qrow = q0 + li;

  const u16* qp = qh + ((size_t)(b * 16 + h) * S + q0) * 64;
  const u16* kp = kh + (size_t)(b * 4 + kvh) * S * 64;
  const u16* vp = vt + (size_t)(b * 4 + kvh) * 64 * S;

  // K/V double-buffered tiles [64 rows][64 cols] u16, source-pre-swizzled:
  // data for logical 16B-slot c of row r lives at physical slot c^(r&7).
  __shared__ __align__(16) u16 Ks[2][64][64];
  __shared__ __align__(16) u16 Vs[2][64][64];
  __shared__ __align__(16) u16 Ps[4][16][64];

  // staging addressing: instr i (i=0,1 per operand), thread tid:
  //   idx = i*256+tid ; row r = idx>>3 ; physical slot = tid&7
  //   logical slot c = (tid&7) ^ (r&7), r&7 == (tid>>3)&7
  const int s_r0 = tid >> 3;            // row for i=0 (i=1: +32)
  const int s_c = (tid & 7) ^ ((tid >> 3) & 7);  // logical slot (both i)

#define STAGE(buf, kb)                                                        \
  {                                                                           \
    const u16* gk = kp + (size_t)((kb) + s_r0) * 64 + s_c * 8;                \
    gl2lds16(gk, &Ks[buf][0][0] + (size_t)tid * 8);                           \
    gl2lds16(gk + (size_t)32 * 64, &Ks[buf][32][0] + (size_t)tid * 8);        \
    const u16* gv = vp + (size_t)s_r0 * S + (kb) + s_c * 8;                   \
    gl2lds16(gv, &Vs[buf][0][0] + (size_t)tid * 8);                           \
    gl2lds16(gv + (size_t)32 * S, &Vs[buf][32][0] + (size_t)tid * 8);         \
  }

  // issue tile-0 staging BEFORE Q loads so vmcnt(4) drains stage0+Q together
  STAGE(0, 0)
  const bf16x8 qf0 = *(const bf16x8*)&qp[li * 64 + lg * 8];
  const bf16x8 qf1 = *(const bf16x8*)&qp[li * 64 + 32 + lg * 8];

  char* psrow = (char*)&Ps[wave][li][0];
  const int swz = li & 7;
  const int rdsw = li & 7;  // row&7 for K/V reads (row = t*16+li)

  const f32x4 fz = {0.f, 0.f, 0.f, 0.f};
  f32x4 o[4];
#pragma unroll
  for (int j = 0; j < 4; j++) o[j] = fz;
  float mrow = -1e30f, lrow = 0.f;

  int buf = 0;
  for (int tt = 0; tt <= qb; ++tt) {
    if (tt < qb) {
      STAGE(buf ^ 1, (tt + 1) * 64)
      asm volatile("s_waitcnt vmcnt(4)" ::: "memory");
    } else {
      asm volatile("s_waitcnt vmcnt(0)" ::: "memory");
    }
    __builtin_amdgcn_s_barrier();
    const int kb = tt * 64;
    // --- S^T = K · Q^T, K from LDS ---
    f32x4 s[4];
#pragma unroll
    for (int t = 0; t < 4; t++) {
      const bf16x8 ka =
          *(const bf16x8*)&Ks[buf][t * 16 + li][((lg) ^ rdsw) * 8];
      const bf16x8 kc =
          *(const bf16x8*)&Ks[buf][t * 16 + li][((lg + 4) ^ rdsw) * 8];
      s[t] = mfma16(ka, qf0, fz);
      s[t] = mfma16(kc, qf1, s[t]);
    }
    // --- mask + scale ---
    float pv[16];
#pragma unroll
    for (int t = 0; t < 4; t++)
#pragma unroll
      for (int r = 0; r < 4; r++) {
        float x = s[t][r] * 0.125f;
        pv[t * 4 + r] = (kb + t * 16 + lg * 4 + r > qrow) ? -1e30f : x;
      }
    // --- online softmax ---
    float mt = pv[0];
#pragma unroll
    for (int i = 1; i < 16; i++) mt = fmaxf(mt, pv[i]);
    mt = fmaxf(mt, __shfl_xor(mt, 16));
    mt = fmaxf(mt, __shfl_xor(mt, 32));
    const float mnew = fmaxf(mrow, mt);
    const float corr = __expf(mrow - mnew);
    mrow = mnew;
    float psum = 0.f;
#pragma unroll
    for (int i = 0; i < 16; i++) {
      pv[i] = __expf(pv[i] - mnew);
      psum += pv[i];
    }
    psum += __shfl_xor(psum, 16);
    psum += __shfl_xor(psum, 32);
    lrow = lrow * corr + psum;
    // --- P -> LDS (bf16, swizzled 8B blocks) ---
#pragma unroll
    for (int t = 0; t < 4; t++) {
      uint2 w;
      w.x = pk2(pv[t * 4 + 0], pv[t * 4 + 1]);
      w.y = pk2(pv[t * 4 + 2], pv[t * 4 + 3]);
      const int c8 = (t * 4 + lg) ^ (swz << 1);
      *(uint2*)(psrow + c8 * 8) = w;
    }
    // --- rescale O ---
#pragma unroll
    for (int r = 0; r < 4; r++) {
      const float cb = __shfl(corr, lg * 4 + r);
      o[0][r] *= cb; o[1][r] *= cb; o[2][r] *= cb; o[3][r] *= cb;
    }
    // --- PV, V from LDS ---
    const bf16x8 pa0 = *(const bf16x8*)(psrow + ((lg + 0) ^ swz) * 16);
    const bf16x8 pa1 = *(const bf16x8*)(psrow + ((lg + 4) ^ swz) * 16);
#pragma unroll
    for (int j = 0; j < 4; j++) {
      const bf16x8 v0 =
          *(const bf16x8*)&Vs[buf][j * 16 + li][((lg) ^ rdsw) * 8];
      const bf16x8 v1 =
          *(const bf16x8*)&Vs[buf][j * 16 + li][((lg + 4) ^ rdsw) * 8];
      o[j] = mfma16(pa0, v0, o[j]);
      o[j] = mfma16(pa1, v1, o[j]);
    }
    // all waves done reading buf before it is restaged next iteration
    __builtin_amdgcn_s_barrier();
    buf ^= 1;
  }
#undef STAGE
  // --- epilogue ---
  float linv[4];
#pragma unroll
  for (int r = 0; r < 4; r++) linv[r] = 1.0f / __shfl(lrow, lg * 4 + r);
#pragma unroll
  for (int j = 0; j < 4; j++)
#pragma unroll
    for (int r = 0; r < 4; r++)
      y[((size_t)(b * S + q0 + lg * 4 + r)) * 1024 + h * 64 + j * 16 + li] =
          f2bf(o[j][r] * linv[r]);
}

extern "C" void kernel_launch(void* const* d_in, const int* in_sizes, int n_in,
                              void* d_out, int out_size, void* d_ws, size_t ws_size,
                              hipStream_t stream) {
  const float* x  = (const float*)d_in[0];
  const float* Wq = (const float*)d_in[1];
  const float* Wk = (const float*)d_in[2];
  const float* Wv = (const float*)d_in[3];
  const float* Wp = (const float*)d_in[4];
  const float* qg = (const float*)d_in[5];
  float* out = (float*)d_out;

  const int S = 2048;
  char* ws = (char*)d_ws;
  u16*   xb   = (u16*)(ws + 0);
  u16*   wqb  = (u16*)(ws + 8388608);
  u16*   wkvb = (u16*)(ws + 10485760);
  u16*   wpb  = (u16*)(ws + 11534336);
  float* qf   = (float*)(ws + 13631488);
  float* kvf  = (float*)(ws + 30408704);
  u16*   qhb  = (u16*)(ws + 38797312);
  u16*   khb  = (u16*)(ws + 47185920);
  u16*   vtb  = (u16*)(ws + 49283072);
  u16*   yb   = (u16*)(ws + 51380224);
  if (ws_size < 59768832) return;

  castf2b<<<16384, 256, 0, stream>>>(x, xb, 4194304);
  castf2b<<<4096, 256, 0, stream>>>(Wq, wqb, 1048576);
  castf2b<<<1024, 256, 0, stream>>>(Wk, wkvb, 262144);
  castf2b<<<1024, 256, 0, stream>>>(Wv, wkvb + 262144, 262144);
  castf2b<<<4096, 256, 0, stream>>>(Wp, wpb, 1048576);

  gemm_bt<<<dim3(8, 32), 256, 0, stream>>>(xb, wqb, qf, 4096, 1024, 1024);
  gemm_bt<<<dim3(4, 32), 256, 0, stream>>>(xb, wkvb, kvf, 4096, 512, 1024);

  rmsrope<<<dim3(4096, 16), 64, 0, stream>>>(qf, 1024, 16, qg, qhb, S);
  rmsrope<<<dim3(4096, 4), 64, 0, stream>>>(kvf, 512, 4, nullptr, khb, S);
  vcast<<<4096, 256, 0, stream>>>(kvf, vtb, S);

  attn4<<<1024, 256, 0, stream>>>(qhb, khb, vtb, yb, S);

  gemm_bt<<<dim3(8, 32), 256, 0, stream>>>(yb, wpb, out, 4096, 1024, 1024);
}

// Round 5
// 179.985 us; speedup vs baseline: 2.0811x; 1.1515x over previous
//
#include <hip/hip_runtime.h>

typedef unsigned short u16;
typedef __bf16 bf16_t;
typedef bf16_t bf16x8 __attribute__((ext_vector_type(8)));
typedef float f32x4 __attribute__((ext_vector_type(4)));
typedef u16 u16x8 __attribute__((ext_vector_type(8)));

__device__ __forceinline__ u16 f2bf(float f) {
  unsigned u = __float_as_uint(f);
  u += 0x7fffu + ((u >> 16) & 1u);
  return (u16)(u >> 16);
}

__device__ __forceinline__ unsigned pk2(float a, float b) {
  return (unsigned)f2bf(a) | ((unsigned)f2bf(b) << 16);
}

__device__ __forceinline__ f32x4 mfma16(bf16x8 a, bf16x8 b, f32x4 c) {
  return __builtin_amdgcn_mfma_f32_16x16x32_bf16(a, b, c, 0, 0, 0);
}

// async global->LDS, 16B per lane; LDS dest resolves to wave-uniform base + lane*16
__device__ __forceinline__ void gl2lds16(const u16* g, u16* l) {
  __builtin_amdgcn_global_load_lds(
      (__attribute__((address_space(1))) void*)(u16*)g,
      (__attribute__((address_space(3))) void*)l, 16, 0, 0);
}

// ---------------- fp32 -> bf16 cast ----------------
__global__ __launch_bounds__(256) void castf2b(const float* __restrict__ in,
                                               u16* __restrict__ out, int n) {
  int i = blockIdx.x * 256 + threadIdx.x;
  if (i < n) out[i] = f2bf(in[i]);
}

// ---------------- GEMM v2: C[M][N] = A[M][K] * B[N][K]^T ----------------
// BK=64 double-buffered LDS via global_load_lds(16B), counted vmcnt, raw barriers.
// Requires M%128==0, N%128==0, K%64==0.
__global__ __launch_bounds__(256) void gemm_bt(const u16* __restrict__ A,
                                               const u16* __restrict__ B,
                                               float* __restrict__ C,
                                               int M, int N, int K) {
  // [128 rows][64 cols] u16 per buffer; 16B-slot s of row r stored at slot s^(r&7)
  __shared__ __align__(16) u16 As[2][128][64];
  __shared__ __align__(16) u16 Bs[2][128][64];
  const int tid = threadIdx.x;
  const int lane = tid & 63;
  const int lg = lane >> 4, li = lane & 15;
  const int wave = tid >> 6;
  const int wr = (wave >> 1) * 64, wc = (wave & 1) * 64;
  const int m0 = blockIdx.y * 128, n0 = blockIdx.x * 128;

  // staging: instr i covers rows i*32 + (tid>>3); logical slot = (tid&7)^((tid>>3)&7)
  const int s_r = tid >> 3;
  const int s_c = (tid & 7) ^ ((tid >> 3) & 7);
  const int rdsw = li & 7;  // row&7 for fragment reads (row = base16*n + li)

#define GSTAGE(buf, k0)                                                       \
  {                                                                           \
    const u16* ga = &A[(size_t)(m0 + s_r) * K + (k0) + s_c * 8];              \
    const u16* gb = &B[(size_t)(n0 + s_r) * K + (k0) + s_c * 8];              \
    gl2lds16(ga,                     &As[buf][0][0]  + (size_t)tid * 8);      \
    gl2lds16(ga + (size_t)32 * K,    &As[buf][32][0] + (size_t)tid * 8);      \
    gl2lds16(ga + (size_t)64 * K,    &As[buf][64][0] + (size_t)tid * 8);      \
    gl2lds16(ga + (size_t)96 * K,    &As[buf][96][0] + (size_t)tid * 8);      \
    gl2lds16(gb,                     &Bs[buf][0][0]  + (size_t)tid * 8);      \
    gl2lds16(gb + (size_t)32 * K,    &Bs[buf][32][0] + (size_t)tid * 8);      \
    gl2lds16(gb + (size_t)64 * K,    &Bs[buf][64][0] + (size_t)tid * 8);      \
    gl2lds16(gb + (size_t)96 * K,    &Bs[buf][96][0] + (size_t)tid * 8);      \
  }

  const f32x4 fz = {0.f, 0.f, 0.f, 0.f};
  f32x4 acc[4][4];
#pragma unroll
  for (int i = 0; i < 4; i++)
#pragma unroll
    for (int j = 0; j < 4; j++) acc[i][j] = fz;

  GSTAGE(0, 0)
  int buf = 0;
  const int nk = K >> 6;
  for (int t = 0; t < nk; ++t) {
    if (t + 1 < nk) {
      GSTAGE(buf ^ 1, (t + 1) * 64)
      asm volatile("s_waitcnt vmcnt(8)" ::: "memory");
    } else {
      asm volatile("s_waitcnt vmcnt(0)" ::: "memory");
    }
    __builtin_amdgcn_s_barrier();
#pragma unroll
    for (int kk = 0; kk < 2; kk++) {
      bf16x8 af[4], bfr[4];
#pragma unroll
      for (int i = 0; i < 4; i++)
        af[i] = *(const bf16x8*)&As[buf][wr + i * 16 + li]
                                   [((kk * 4 + lg) ^ rdsw) * 8];
#pragma unroll
      for (int j = 0; j < 4; j++)
        bfr[j] = *(const bf16x8*)&Bs[buf][wc + j * 16 + li]
                                    [((kk * 4 + lg) ^ rdsw) * 8];
#pragma unroll
      for (int i = 0; i < 4; i++)
#pragma unroll
        for (int j = 0; j < 4; j++) acc[i][j] = mfma16(af[i], bfr[j], acc[i][j]);
    }
    __builtin_amdgcn_s_barrier();
    buf ^= 1;
  }
#undef GSTAGE
#pragma unroll
  for (int i = 0; i < 4; i++)
#pragma unroll
    for (int j = 0; j < 4; j++)
#pragma unroll
      for (int r = 0; r < 4; r++)
        C[(size_t)(m0 + wr + i * 16 + lg * 4 + r) * N + n0 + wc + j * 16 + li] =
            acc[i][j][r];
}

// ---------------- fused RMSNorm + RoPE + gain ----------------
__global__ __launch_bounds__(64) void rmsrope(const float* __restrict__ in, int ld,
                                              int nh, const float* __restrict__ gain,
                                              u16* __restrict__ out, int S) {
  const int row = blockIdx.x;
  const int h = blockIdx.y;
  const int t = threadIdx.x;
  const float v = in[(size_t)row * ld + h * 64 + t];
  float ss = v * v;
#pragma unroll
  for (int m = 1; m < 64; m <<= 1) ss += __shfl_xor(ss, m);
  const float vn = v * rsqrtf(ss * (1.0f / 64.0f) + 1.1920929e-07f);
  const float partner = __shfl_xor(vn, 32);
  const int i = t & 31;
  const float inv = powf(10000.0f, -(float)(2 * i) / 64.0f);
  const int b = row / S;
  const int s = row - b * S;
  const float fr = (float)s * inv;
  float sn, cs;
  sincosf(fr, &sn, &cs);
  float o = (t < 32) ? (vn * cs + partner * sn) : (vn * cs - partner * sn);
  if (gain) o *= gain[h];
  out[((size_t)(b * nh + h) * S + s) * 64 + t] = f2bf(o);
}

// ---------------- V cast+transpose ----------------
__global__ __launch_bounds__(256) void vcast(const float* __restrict__ kvf,
                                             u16* __restrict__ vt, int S) {
  int idx = blockIdx.x * 256 + threadIdx.x;
  int row = idx >> 8;
  int c = idx & 255;
  int b = row / S, s = row - b * S;
  int kv = c >> 6, d = c & 63;
  vt[((size_t)(b * 4 + kv) * 64 + d) * S + s] = f2bf(kvf[(size_t)row * 512 + 256 + c]);
}

// ---------------- flash attention v4: LDS-staged K/V, dbuf + counted vmcnt --
__global__ __launch_bounds__(256) void attn4(const u16* __restrict__ qh,
                                             const u16* __restrict__ kh,
                                             const u16* __restrict__ vt,
                                             u16* __restrict__ y, int S) {
  const int bh = blockIdx.x & 31;
  const int qb = blockIdx.x >> 5;
  const int h = bh & 15, b = bh >> 4;
  const int kvh = h >> 2;
  const int tid = threadIdx.x;
  const int wave = tid >> 6;
  const int lane = tid & 63;
  const int lg = lane >> 4, li = lane & 15;
  const int q0 = qb * 64 + wave * 16;
  const int qrow = q0 + li;

  const u16* qp = qh + ((size_t)(b * 16 + h) * S + q0) * 64;
  const u16* kp = kh + (size_t)(b * 4 + kvh) * S * 64;
  const u16* vp = vt + (size_t)(b * 4 + kvh) * 64 * S;

  __shared__ __align__(16) u16 Ks[2][64][64];
  __shared__ __align__(16) u16 Vs[2][64][64];
  __shared__ __align__(16) u16 Ps[4][16][64];

  const int s_r0 = tid >> 3;
  const int s_c = (tid & 7) ^ ((tid >> 3) & 7);

#define STAGE(buf, kb)                                                        \
  {                                                                           \
    const u16* gk = kp + (size_t)((kb) + s_r0) * 64 + s_c * 8;                \
    gl2lds16(gk, &Ks[buf][0][0] + (size_t)tid * 8);                           \
    gl2lds16(gk + (size_t)32 * 64, &Ks[buf][32][0] + (size_t)tid * 8);        \
    const u16* gv = vp + (size_t)s_r0 * S + (kb) + s_c * 8;                   \
    gl2lds16(gv, &Vs[buf][0][0] + (size_t)tid * 8);                           \
    gl2lds16(gv + (size_t)32 * S, &Vs[buf][32][0] + (size_t)tid * 8);         \
  }

  STAGE(0, 0)
  const bf16x8 qf0 = *(const bf16x8*)&qp[li * 64 + lg * 8];
  const bf16x8 qf1 = *(const bf16x8*)&qp[li * 64 + 32 + lg * 8];

  char* psrow = (char*)&Ps[wave][li][0];
  const int swz = li & 7;
  const int rdsw = li & 7;

  const f32x4 fz = {0.f, 0.f, 0.f, 0.f};
  f32x4 o[4];
#pragma unroll
  for (int j = 0; j < 4; j++) o[j] = fz;
  float mrow = -1e30f, lrow = 0.f;

  int buf = 0;
  for (int tt = 0; tt <= qb; ++tt) {
    if (tt < qb) {
      STAGE(buf ^ 1, (tt + 1) * 64)
      asm volatile("s_waitcnt vmcnt(4)" ::: "memory");
    } else {
      asm volatile("s_waitcnt vmcnt(0)" ::: "memory");
    }
    __builtin_amdgcn_s_barrier();
    const int kb = tt * 64;
    f32x4 s[4];
#pragma unroll
    for (int t = 0; t < 4; t++) {
      const bf16x8 ka =
          *(const bf16x8*)&Ks[buf][t * 16 + li][((lg) ^ rdsw) * 8];
      const bf16x8 kc =
          *(const bf16x8*)&Ks[buf][t * 16 + li][((lg + 4) ^ rdsw) * 8];
      s[t] = mfma16(ka, qf0, fz);
      s[t] = mfma16(kc, qf1, s[t]);
    }
    float pv[16];
#pragma unroll
    for (int t = 0; t < 4; t++)
#pragma unroll
      for (int r = 0; r < 4; r++) {
        float x = s[t][r] * 0.125f;
        pv[t * 4 + r] = (kb + t * 16 + lg * 4 + r > qrow) ? -1e30f : x;
      }
    float mt = pv[0];
#pragma unroll
    for (int i = 1; i < 16; i++) mt = fmaxf(mt, pv[i]);
    mt = fmaxf(mt, __shfl_xor(mt, 16));
    mt = fmaxf(mt, __shfl_xor(mt, 32));
    const float mnew = fmaxf(mrow, mt);
    const float corr = __expf(mrow - mnew);
    mrow = mnew;
    float psum = 0.f;
#pragma unroll
    for (int i = 0; i < 16; i++) {
      pv[i] = __expf(pv[i] - mnew);
      psum += pv[i];
    }
    psum += __shfl_xor(psum, 16);
    psum += __shfl_xor(psum, 32);
    lrow = lrow * corr + psum;
#pragma unroll
    for (int t = 0; t < 4; t++) {
      uint2 w;
      w.x = pk2(pv[t * 4 + 0], pv[t * 4 + 1]);
      w.y = pk2(pv[t * 4 + 2], pv[t * 4 + 3]);
      const int c8 = (t * 4 + lg) ^ (swz << 1);
      *(uint2*)(psrow + c8 * 8) = w;
    }
#pragma unroll
    for (int r = 0; r < 4; r++) {
      const float cb = __shfl(corr, lg * 4 + r);
      o[0][r] *= cb; o[1][r] *= cb; o[2][r] *= cb; o[3][r] *= cb;
    }
    const bf16x8 pa0 = *(const bf16x8*)(psrow + ((lg + 0) ^ swz) * 16);
    const bf16x8 pa1 = *(const bf16x8*)(psrow + ((lg + 4) ^ swz) * 16);
#pragma unroll
    for (int j = 0; j < 4; j++) {
      const bf16x8 v0 =
          *(const bf16x8*)&Vs[buf][j * 16 + li][((lg) ^ rdsw) * 8];
      const bf16x8 v1 =
          *(const bf16x8*)&Vs[buf][j * 16 + li][((lg + 4) ^ rdsw) * 8];
      o[j] = mfma16(pa0, v0, o[j]);
      o[j] = mfma16(pa1, v1, o[j]);
    }
    __builtin_amdgcn_s_barrier();
    buf ^= 1;
  }
#undef STAGE
  float linv[4];
#pragma unroll
  for (int r = 0; r < 4; r++) linv[r] = 1.0f / __shfl(lrow, lg * 4 + r);
#pragma unroll
  for (int j = 0; j < 4; j++)
#pragma unroll
    for (int r = 0; r < 4; r++)
      y[((size_t)(b * S + q0 + lg * 4 + r)) * 1024 + h * 64 + j * 16 + li] =
          f2bf(o[j][r] * linv[r]);
}

extern "C" void kernel_launch(void* const* d_in, const int* in_sizes, int n_in,
                              void* d_out, int out_size, void* d_ws, size_t ws_size,
                              hipStream_t stream) {
  const float* x  = (const float*)d_in[0];
  const float* Wq = (const float*)d_in[1];
  const float* Wk = (const float*)d_in[2];
  const float* Wv = (const float*)d_in[3];
  const float* Wp = (const float*)d_in[4];
  const float* qg = (const float*)d_in[5];
  float* out = (float*)d_out;

  const int S = 2048;
  char* ws = (char*)d_ws;
  u16*   xb   = (u16*)(ws + 0);
  u16*   wqb  = (u16*)(ws + 8388608);
  u16*   wkvb = (u16*)(ws + 10485760);
  u16*   wpb  = (u16*)(ws + 11534336);
  float* qf   = (float*)(ws + 13631488);
  float* kvf  = (float*)(ws + 30408704);
  u16*   qhb  = (u16*)(ws + 38797312);
  u16*   khb  = (u16*)(ws + 47185920);
  u16*   vtb  = (u16*)(ws + 49283072);
  u16*   yb   = (u16*)(ws + 51380224);
  if (ws_size < 59768832) return;

  castf2b<<<16384, 256, 0, stream>>>(x, xb, 4194304);
  castf2b<<<4096, 256, 0, stream>>>(Wq, wqb, 1048576);
  castf2b<<<1024, 256, 0, stream>>>(Wk, wkvb, 262144);
  castf2b<<<1024, 256, 0, stream>>>(Wv, wkvb + 262144, 262144);
  castf2b<<<4096, 256, 0, stream>>>(Wp, wpb, 1048576);

  gemm_bt<<<dim3(8, 32), 256, 0, stream>>>(xb, wqb, qf, 4096, 1024, 1024);
  gemm_bt<<<dim3(4, 32), 256, 0, stream>>>(xb, wkvb, kvf, 4096, 512, 1024);

  rmsrope<<<dim3(4096, 16), 64, 0, stream>>>(qf, 1024, 16, qg, qhb, S);
  rmsrope<<<dim3(4096, 4), 64, 0, stream>>>(kvf, 512, 4, nullptr, khb, S);
  vcast<<<4096, 256, 0, stream>>>(kvf, vtb, S);

  attn4<<<1024, 256, 0, stream>>>(qhb, khb, vtb, yb, S);

  gemm_bt<<<dim3(8, 32), 256, 0, stream>>>(yb, wpb, out, 4096, 1024, 1024);
}

// Round 6
// 140.111 us; speedup vs baseline: 2.6734x; 1.2846x over previous
//
#include <hip/hip_runtime.h>

typedef unsigned short u16;
typedef __bf16 bf16_t;
typedef bf16_t bf16x8 __attribute__((ext_vector_type(8)));
typedef float f32x4 __attribute__((ext_vector_type(4)));
typedef u16 u16x8 __attribute__((ext_vector_type(8)));

__device__ __forceinline__ u16 f2bf(float f) {
  unsigned u = __float_as_uint(f);
  u += 0x7fffu + ((u >> 16) & 1u);
  return (u16)(u >> 16);
}

// packed f32x2 -> bf16x2 (RNE), single instruction
__device__ __forceinline__ unsigned cvtpk(float lo, float hi) {
  unsigned r;
  asm("v_cvt_pk_bf16_f32 %0, %1, %2" : "=v"(r) : "v"(lo), "v"(hi));
  return r;
}

__device__ __forceinline__ f32x4 mfma16(bf16x8 a, bf16x8 b, f32x4 c) {
  return __builtin_amdgcn_mfma_f32_16x16x32_bf16(a, b, c, 0, 0, 0);
}

__device__ __forceinline__ void gl2lds16(const u16* g, u16* l) {
  __builtin_amdgcn_global_load_lds(
      (__attribute__((address_space(1))) void*)(u16*)g,
      (__attribute__((address_space(3))) void*)l, 16, 0, 0);
}

// ---------------- fp32 -> bf16 cast, 8 elems/thread ----------------
__global__ __launch_bounds__(256) void castf2b(const float* __restrict__ in,
                                               u16* __restrict__ out, int n) {
  int i = (blockIdx.x * 256 + threadIdx.x) * 8;
  if (i < n) {
    float4 a = *(const float4*)&in[i];
    float4 b = *(const float4*)&in[i + 4];
    uint4 o;
    o.x = cvtpk(a.x, a.y);
    o.y = cvtpk(a.z, a.w);
    o.z = cvtpk(b.x, b.y);
    o.w = cvtpk(b.z, b.w);
    *(uint4*)&out[i] = o;
  }
}

// ---------------- cos/sin table: tbl[s*32+i] = (cos, sin)(s * 10000^(-i/32))
__global__ __launch_bounds__(256) void trigtab(float2* __restrict__ tbl, int S) {
  int idx = blockIdx.x * 256 + threadIdx.x;
  if (idx < S * 32) {
    int s = idx >> 5, i = idx & 31;
    float inv = exp2f(-(float)i * (13.287712379549449f / 32.0f));
    float fr = (float)s * inv;
    float sn, cs;
    sincosf(fr, &sn, &cs);
    tbl[idx] = make_float2(cs, sn);
  }
}

// ---------------- GEMM v2: C[M][N] = A[M][K] * B[N][K]^T ----------------
__global__ __launch_bounds__(256) void gemm_bt(const u16* __restrict__ A,
                                               const u16* __restrict__ B,
                                               float* __restrict__ C,
                                               int M, int N, int K) {
  __shared__ __align__(16) u16 As[2][128][64];
  __shared__ __align__(16) u16 Bs[2][128][64];
  const int tid = threadIdx.x;
  const int lane = tid & 63;
  const int lg = lane >> 4, li = lane & 15;
  const int wave = tid >> 6;
  const int wr = (wave >> 1) * 64, wc = (wave & 1) * 64;
  const int m0 = blockIdx.y * 128, n0 = blockIdx.x * 128;

  const int s_r = tid >> 3;
  const int s_c = (tid & 7) ^ ((tid >> 3) & 7);
  const int rdsw = li & 7;

#define GSTAGE(buf, k0)                                                       \
  {                                                                           \
    const u16* ga = &A[(size_t)(m0 + s_r) * K + (k0) + s_c * 8];              \
    const u16* gb = &B[(size_t)(n0 + s_r) * K + (k0) + s_c * 8];              \
    gl2lds16(ga,                  &As[buf][0][0]  + (size_t)tid * 8);         \
    gl2lds16(ga + (size_t)32 * K, &As[buf][32][0] + (size_t)tid * 8);         \
    gl2lds16(ga + (size_t)64 * K, &As[buf][64][0] + (size_t)tid * 8);         \
    gl2lds16(ga + (size_t)96 * K, &As[buf][96][0] + (size_t)tid * 8);         \
    gl2lds16(gb,                  &Bs[buf][0][0]  + (size_t)tid * 8);         \
    gl2lds16(gb + (size_t)32 * K, &Bs[buf][32][0] + (size_t)tid * 8);         \
    gl2lds16(gb + (size_t)64 * K, &Bs[buf][64][0] + (size_t)tid * 8);         \
    gl2lds16(gb + (size_t)96 * K, &Bs[buf][96][0] + (size_t)tid * 8);         \
  }

  const f32x4 fz = {0.f, 0.f, 0.f, 0.f};
  f32x4 acc[4][4];
#pragma unroll
  for (int i = 0; i < 4; i++)
#pragma unroll
    for (int j = 0; j < 4; j++) acc[i][j] = fz;

  GSTAGE(0, 0)
  int buf = 0;
  const int nk = K >> 6;
  for (int t = 0; t < nk; ++t) {
    if (t + 1 < nk) {
      GSTAGE(buf ^ 1, (t + 1) * 64)
      asm volatile("s_waitcnt vmcnt(8)" ::: "memory");
    } else {
      asm volatile("s_waitcnt vmcnt(0)" ::: "memory");
    }
    __builtin_amdgcn_s_barrier();
#pragma unroll
    for (int kk = 0; kk < 2; kk++) {
      bf16x8 af[4], bfr[4];
#pragma unroll
      for (int i = 0; i < 4; i++)
        af[i] = *(const bf16x8*)&As[buf][wr + i * 16 + li]
                                   [((kk * 4 + lg) ^ rdsw) * 8];
#pragma unroll
      for (int j = 0; j < 4; j++)
        bfr[j] = *(const bf16x8*)&Bs[buf][wc + j * 16 + li]
                                    [((kk * 4 + lg) ^ rdsw) * 8];
      __builtin_amdgcn_s_setprio(1);
#pragma unroll
      for (int i = 0; i < 4; i++)
#pragma unroll
        for (int j = 0; j < 4; j++) acc[i][j] = mfma16(af[i], bfr[j], acc[i][j]);
      __builtin_amdgcn_s_setprio(0);
    }
    __builtin_amdgcn_s_barrier();
    buf ^= 1;
  }
#undef GSTAGE
#pragma unroll
  for (int i = 0; i < 4; i++)
#pragma unroll
    for (int j = 0; j < 4; j++)
#pragma unroll
      for (int r = 0; r < 4; r++)
        C[(size_t)(m0 + wr + i * 16 + lg * 4 + r) * N + n0 + wc + j * 16 + li] =
            acc[i][j][r];
}

// ---------------- fused RMSNorm + RoPE + gain + scale ----------------
// one wave per (row, head); 4 rows per 256-thread block
__global__ __launch_bounds__(256) void rmsrope(const float* __restrict__ in, int ld,
                                               int nh, const float* __restrict__ gain,
                                               u16* __restrict__ out, int S,
                                               const float2* __restrict__ tbl,
                                               float scale) {
  const int w = threadIdx.x >> 6;
  const int t = threadIdx.x & 63;
  const int row = blockIdx.x * 4 + w;
  const int h = blockIdx.y;
  const float v = in[(size_t)row * ld + h * 64 + t];
  float ss = v * v;
#pragma unroll
  for (int m = 1; m < 64; m <<= 1) ss += __shfl_xor(ss, m);
  const float vn = v * rsqrtf(ss * (1.0f / 64.0f) + 1.1920929e-07f);
  const float partner = __shfl_xor(vn, 32);
  const int b = row / S;
  const int s = row - b * S;
  const float2 cs2 = tbl[s * 32 + (t & 31)];
  float o = (t < 32) ? (vn * cs2.x + partner * cs2.y)
                     : (vn * cs2.x - partner * cs2.y);
  o *= scale;
  if (gain) o *= gain[h];
  out[((size_t)(b * nh + h) * S + s) * 64 + t] = f2bf(o);
}

// ---------------- V cast+transpose: qf cols 1280..1535 -> [B][4][64][S] -----
__global__ __launch_bounds__(256) void vcast(const float* __restrict__ qf,
                                             u16* __restrict__ vt, int S) {
  int idx = blockIdx.x * 256 + threadIdx.x;
  int row = idx >> 8;
  int c = idx & 255;
  int b = row / S, s = row - b * S;
  int kv = c >> 6, d = c & 63;
  vt[((size_t)(b * 4 + kv) * 64 + d) * S + s] =
      f2bf(qf[(size_t)row * 1536 + 1280 + c]);
}

// ---------------- flash attention v5 ----------------
// qh: [B][16][S][64] (pre-scaled by 0.125), kh: [B][4][S][64], vt: [B][4][64][S]
__global__ __launch_bounds__(256) void attn5(const u16* __restrict__ qh,
                                             const u16* __restrict__ kh,
                                             const u16* __restrict__ vt,
                                             u16* __restrict__ y, int S) {
  const int bh = blockIdx.x & 31;
  const int tt4 = blockIdx.x >> 5;  // 0..31
  const int d = tt4 & 7, u = tt4 >> 3;
  // balanced per-CU map: qb in {d, 15-d, 16+d, 31-d} -> 66 iters per CU
  const int qb = (u == 0) ? d : (u == 1) ? 15 - d : (u == 2) ? 16 + d : 31 - d;
  const int h = bh & 15, b = bh >> 4;
  const int kvh = h >> 2;
  const int tid = threadIdx.x;
  const int wave = tid >> 6;
  const int lane = tid & 63;
  const int lg = lane >> 4, li = lane & 15;
  const int q0 = qb * 64 + wave * 16;
  const int qrow = q0 + li;

  const u16* qp = qh + ((size_t)(b * 16 + h) * S + q0) * 64;
  const u16* kp = kh + (size_t)(b * 4 + kvh) * S * 64;
  const u16* vp = vt + (size_t)(b * 4 + kvh) * 64 * S;

  __shared__ __align__(16) u16 Ks[2][64][64];
  __shared__ __align__(16) u16 Vs[2][64][64];
  __shared__ __align__(16) u16 Ps[4][16][64];

  const int s_r0 = tid >> 3;
  const int s_c = (tid & 7) ^ ((tid >> 3) & 7);

#define STAGE(buf, kb)                                                        \
  {                                                                           \
    const u16* gk = kp + (size_t)((kb) + s_r0) * 64 + s_c * 8;                \
    gl2lds16(gk, &Ks[buf][0][0] + (size_t)tid * 8);                           \
    gl2lds16(gk + (size_t)32 * 64, &Ks[buf][32][0] + (size_t)tid * 8);        \
    const u16* gv = vp + (size_t)s_r0 * S + (kb) + s_c * 8;                   \
    gl2lds16(gv, &Vs[buf][0][0] + (size_t)tid * 8);                           \
    gl2lds16(gv + (size_t)32 * S, &Vs[buf][32][0] + (size_t)tid * 8);         \
  }

  STAGE(0, 0)
  const bf16x8 qf0 = *(const bf16x8*)&qp[li * 64 + lg * 8];
  const bf16x8 qf1 = *(const bf16x8*)&qp[li * 64 + 32 + lg * 8];

  char* psrow = (char*)&Ps[wave][li][0];
  const int swz = li & 7;
  const int rdsw = li & 7;

  const f32x4 fz = {0.f, 0.f, 0.f, 0.f};
  f32x4 o[4];
#pragma unroll
  for (int j = 0; j < 4; j++) o[j] = fz;
  float mrow = -1e30f, lrow = 0.f;

  int buf = 0;
  for (int tt = 0; tt <= qb; ++tt) {
    if (tt < qb) {
      STAGE(buf ^ 1, (tt + 1) * 64)
      asm volatile("s_waitcnt vmcnt(4)" ::: "memory");
    } else {
      asm volatile("s_waitcnt vmcnt(0)" ::: "memory");
    }
    __builtin_amdgcn_s_barrier();
    const int kb = tt * 64;
    f32x4 s[4];
    __builtin_amdgcn_s_setprio(1);
#pragma unroll
    for (int t = 0; t < 4; t++) {
      const bf16x8 ka =
          *(const bf16x8*)&Ks[buf][t * 16 + li][((lg) ^ rdsw) * 8];
      const bf16x8 kc =
          *(const bf16x8*)&Ks[buf][t * 16 + li][((lg + 4) ^ rdsw) * 8];
      s[t] = mfma16(ka, qf0, fz);
      s[t] = mfma16(kc, qf1, s[t]);
    }
    __builtin_amdgcn_s_setprio(0);
    float pv[16];
    if (tt < qb) {  // interior tile: no masking needed (block-uniform branch)
#pragma unroll
      for (int t = 0; t < 4; t++)
#pragma unroll
        for (int r = 0; r < 4; r++) pv[t * 4 + r] = s[t][r];
    } else {
#pragma unroll
      for (int t = 0; t < 4; t++)
#pragma unroll
        for (int r = 0; r < 4; r++)
          pv[t * 4 + r] =
              (kb + t * 16 + lg * 4 + r > qrow) ? -1e30f : s[t][r];
    }
    // tree max over 16, then across lg
    float m8[8];
#pragma unroll
    for (int i = 0; i < 8; i++) m8[i] = fmaxf(pv[i], pv[i + 8]);
    float m4a = fmaxf(m8[0], m8[4]), m4b = fmaxf(m8[1], m8[5]);
    float m4c = fmaxf(m8[2], m8[6]), m4d = fmaxf(m8[3], m8[7]);
    float mt = fmaxf(fmaxf(m4a, m4b), fmaxf(m4c, m4d));
    mt = fmaxf(mt, __shfl_xor(mt, 16));
    mt = fmaxf(mt, __shfl_xor(mt, 32));
    // defer-max: only rescale when the running max moved materially
    if (!__all(mt <= mrow + 8.f)) {
      const float mnew = fmaxf(mrow, mt);
      const float corr = __expf(mrow - mnew);
      mrow = mnew;
      lrow *= corr;
#pragma unroll
      for (int r = 0; r < 4; r++) {
        const float cb = __shfl(corr, lg * 4 + r);
        o[0][r] *= cb; o[1][r] *= cb; o[2][r] *= cb; o[3][r] *= cb;
      }
    }
    float psum = 0.f;
#pragma unroll
    for (int i = 0; i < 16; i++) {
      pv[i] = __expf(pv[i] - mrow);
      psum += pv[i];
    }
    psum += __shfl_xor(psum, 16);
    psum += __shfl_xor(psum, 32);
    lrow += psum;
    // P -> LDS (packed bf16 via cvt_pk, swizzled 8B blocks)
#pragma unroll
    for (int t = 0; t < 4; t++) {
      uint2 w;
      w.x = cvtpk(pv[t * 4 + 0], pv[t * 4 + 1]);
      w.y = cvtpk(pv[t * 4 + 2], pv[t * 4 + 3]);
      const int c8 = (t * 4 + lg) ^ (swz << 1);
      *(uint2*)(psrow + c8 * 8) = w;
    }
    const bf16x8 pa0 = *(const bf16x8*)(psrow + ((lg + 0) ^ swz) * 16);
    const bf16x8 pa1 = *(const bf16x8*)(psrow + ((lg + 4) ^ swz) * 16);
    __builtin_amdgcn_s_setprio(1);
#pragma unroll
    for (int j = 0; j < 4; j++) {
      const bf16x8 v0 =
          *(const bf16x8*)&Vs[buf][j * 16 + li][((lg) ^ rdsw) * 8];
      const bf16x8 v1 =
          *(const bf16x8*)&Vs[buf][j * 16 + li][((lg + 4) ^ rdsw) * 8];
      o[j] = mfma16(pa0, v0, o[j]);
      o[j] = mfma16(pa1, v1, o[j]);
    }
    __builtin_amdgcn_s_setprio(0);
    __builtin_amdgcn_s_barrier();
    buf ^= 1;
  }
#undef STAGE
  float linv[4];
#pragma unroll
  for (int r = 0; r < 4; r++) linv[r] = 1.0f / __shfl(lrow, lg * 4 + r);
#pragma unroll
  for (int j = 0; j < 4; j++)
#pragma unroll
    for (int r = 0; r < 4; r++)
      y[((size_t)(b * S + q0 + lg * 4 + r)) * 1024 + h * 64 + j * 16 + li] =
          f2bf(o[j][r] * linv[r]);
}

extern "C" void kernel_launch(void* const* d_in, const int* in_sizes, int n_in,
                              void* d_out, int out_size, void* d_ws, size_t ws_size,
                              hipStream_t stream) {
  const float* x  = (const float*)d_in[0];
  const float* Wq = (const float*)d_in[1];
  const float* Wk = (const float*)d_in[2];
  const float* Wv = (const float*)d_in[3];
  const float* Wp = (const float*)d_in[4];
  const float* qg = (const float*)d_in[5];
  float* out = (float*)d_out;

  const int S = 2048;
  char* ws = (char*)d_ws;
  u16*   xb   = (u16*)(ws + 0);            // 8 MB
  u16*   wallb= (u16*)(ws + 8388608);      // [Wq;Wk;Wv] = [1536][1024] bf16 (3 MB)
  u16*   wpb  = (u16*)(ws + 11534336);     // 2 MB
  float* qf   = (float*)(ws + 13631488);   // [4096][1536] f32 (24 MB) -> 38797312
  u16*   qhb  = (u16*)(ws + 38797312);     // 8 MB
  u16*   khb  = (u16*)(ws + 47185920);     // 2 MB
  u16*   vtb  = (u16*)(ws + 49283072);     // 2 MB
  u16*   yb   = (u16*)(ws + 51380224);     // 8 MB -> 59768832
  // trig table reuses the (then-dead) QKV-weight region after the QKV GEMM
  float2* tbl = (float2*)(ws + 8388608);   // 512 KB
  if (ws_size < 59768832) return;

  castf2b<<<2048, 256, 0, stream>>>(x, xb, 4194304);
  castf2b<<<512, 256, 0, stream>>>(Wq, wallb, 1048576);
  castf2b<<<128, 256, 0, stream>>>(Wk, wallb + 1048576, 262144);
  castf2b<<<128, 256, 0, stream>>>(Wv, wallb + 1310720, 262144);
  castf2b<<<512, 256, 0, stream>>>(Wp, wpb, 1048576);

  // fused QKV projection: [q|k|v] = x [Wq;Wk;Wv]^T
  gemm_bt<<<dim3(12, 32), 256, 0, stream>>>(xb, wallb, qf, 4096, 1536, 1024);

  trigtab<<<256, 256, 0, stream>>>(tbl, S);

  rmsrope<<<dim3(1024, 16), 256, 0, stream>>>(qf, 1536, 16, qg, qhb, S, tbl, 0.125f);
  rmsrope<<<dim3(1024, 4), 256, 0, stream>>>(qf + 1024, 1536, 4, nullptr, khb, S, tbl, 1.0f);
  vcast<<<4096, 256, 0, stream>>>(qf, vtb, S);

  attn5<<<1024, 256, 0, stream>>>(qhb, khb, vtb, yb, S);

  gemm_bt<<<dim3(8, 32), 256, 0, stream>>>(yb, wpb, out, 4096, 1024, 1024);
}

// Round 7
// 138.548 us; speedup vs baseline: 2.7036x; 1.0113x over previous
//
#include <hip/hip_runtime.h>

typedef unsigned short u16;
typedef __bf16 bf16_t;
typedef bf16_t bf16x8 __attribute__((ext_vector_type(8)));
typedef float f32x4 __attribute__((ext_vector_type(4)));
typedef u16 u16x8 __attribute__((ext_vector_type(8)));
typedef u16 u16x4 __attribute__((ext_vector_type(4)));

__device__ __forceinline__ u16 f2bf(float f) {
  unsigned u = __float_as_uint(f);
  u += 0x7fffu + ((u >> 16) & 1u);
  return (u16)(u >> 16);
}

// packed f32x2 -> bf16x2 (RNE), single instruction
__device__ __forceinline__ unsigned cvtpk(float lo, float hi) {
  unsigned r;
  asm("v_cvt_pk_bf16_f32 %0, %1, %2" : "=v"(r) : "v"(lo), "v"(hi));
  return r;
}

__device__ __forceinline__ f32x4 mfma16(bf16x8 a, bf16x8 b, f32x4 c) {
  return __builtin_amdgcn_mfma_f32_16x16x32_bf16(a, b, c, 0, 0, 0);
}

__device__ __forceinline__ void gl2lds16(const u16* g, u16* l) {
  __builtin_amdgcn_global_load_lds(
      (__attribute__((address_space(1))) void*)(u16*)g,
      (__attribute__((address_space(3))) void*)l, 16, 0, 0);
}

// ---------------- fp32 -> bf16 cast, 8 elems/thread ----------------
__global__ __launch_bounds__(256) void castf2b(const float* __restrict__ in,
                                               u16* __restrict__ out, int n) {
  int i = (blockIdx.x * 256 + threadIdx.x) * 8;
  if (i < n) {
    float4 a = *(const float4*)&in[i];
    float4 b = *(const float4*)&in[i + 4];
    uint4 o;
    o.x = cvtpk(a.x, a.y);
    o.y = cvtpk(a.z, a.w);
    o.z = cvtpk(b.x, b.y);
    o.w = cvtpk(b.z, b.w);
    *(uint4*)&out[i] = o;
  }
}

// ---------------- cos/sin table: tbl[s*32+i] = (cos, sin)(s * 10000^(-i/32))
__global__ __launch_bounds__(256) void trigtab(float2* __restrict__ tbl, int S) {
  int idx = blockIdx.x * 256 + threadIdx.x;
  if (idx < S * 32) {
    int s = idx >> 5, i = idx & 31;
    float inv = exp2f(-(float)i * (13.287712379549449f / 32.0f));
    float fr = (float)s * inv;
    float sn, cs;
    sincosf(fr, &sn, &cs);
    tbl[idx] = make_float2(cs, sn);
  }
}

// ---------------- GEMM v2: C[M][N] = A[M][K] * B[N][K]^T ----------------
__global__ __launch_bounds__(256) void gemm_bt(const u16* __restrict__ A,
                                               const u16* __restrict__ B,
                                               float* __restrict__ C,
                                               int M, int N, int K) {
  __shared__ __align__(16) u16 As[2][128][64];
  __shared__ __align__(16) u16 Bs[2][128][64];
  const int tid = threadIdx.x;
  const int lane = tid & 63;
  const int lg = lane >> 4, li = lane & 15;
  const int wave = tid >> 6;
  const int wr = (wave >> 1) * 64, wc = (wave & 1) * 64;
  const int m0 = blockIdx.y * 128, n0 = blockIdx.x * 128;

  const int s_r = tid >> 3;
  const int s_c = (tid & 7) ^ ((tid >> 3) & 7);
  const int rdsw = li & 7;

#define GSTAGE(buf, k0)                                                       \
  {                                                                           \
    const u16* ga = &A[(size_t)(m0 + s_r) * K + (k0) + s_c * 8];              \
    const u16* gb = &B[(size_t)(n0 + s_r) * K + (k0) + s_c * 8];              \
    gl2lds16(ga,                  &As[buf][0][0]  + (size_t)tid * 8);         \
    gl2lds16(ga + (size_t)32 * K, &As[buf][32][0] + (size_t)tid * 8);         \
    gl2lds16(ga + (size_t)64 * K, &As[buf][64][0] + (size_t)tid * 8);         \
    gl2lds16(ga + (size_t)96 * K, &As[buf][96][0] + (size_t)tid * 8);         \
    gl2lds16(gb,                  &Bs[buf][0][0]  + (size_t)tid * 8);         \
    gl2lds16(gb + (size_t)32 * K, &Bs[buf][32][0] + (size_t)tid * 8);         \
    gl2lds16(gb + (size_t)64 * K, &Bs[buf][64][0] + (size_t)tid * 8);         \
    gl2lds16(gb + (size_t)96 * K, &Bs[buf][96][0] + (size_t)tid * 8);         \
  }

  const f32x4 fz = {0.f, 0.f, 0.f, 0.f};
  f32x4 acc[4][4];
#pragma unroll
  for (int i = 0; i < 4; i++)
#pragma unroll
    for (int j = 0; j < 4; j++) acc[i][j] = fz;

  GSTAGE(0, 0)
  int buf = 0;
  const int nk = K >> 6;
  for (int t = 0; t < nk; ++t) {
    if (t + 1 < nk) {
      GSTAGE(buf ^ 1, (t + 1) * 64)
      asm volatile("s_waitcnt vmcnt(8)" ::: "memory");
    } else {
      asm volatile("s_waitcnt vmcnt(0)" ::: "memory");
    }
    __builtin_amdgcn_s_barrier();
#pragma unroll
    for (int kk = 0; kk < 2; kk++) {
      bf16x8 af[4], bfr[4];
#pragma unroll
      for (int i = 0; i < 4; i++)
        af[i] = *(const bf16x8*)&As[buf][wr + i * 16 + li]
                                   [((kk * 4 + lg) ^ rdsw) * 8];
#pragma unroll
      for (int j = 0; j < 4; j++)
        bfr[j] = *(const bf16x8*)&Bs[buf][wc + j * 16 + li]
                                    [((kk * 4 + lg) ^ rdsw) * 8];
      __builtin_amdgcn_s_setprio(1);
#pragma unroll
      for (int i = 0; i < 4; i++)
#pragma unroll
        for (int j = 0; j < 4; j++) acc[i][j] = mfma16(af[i], bfr[j], acc[i][j]);
      __builtin_amdgcn_s_setprio(0);
    }
    __builtin_amdgcn_s_barrier();
    buf ^= 1;
  }
#undef GSTAGE
#pragma unroll
  for (int i = 0; i < 4; i++)
#pragma unroll
    for (int j = 0; j < 4; j++)
#pragma unroll
      for (int r = 0; r < 4; r++)
        C[(size_t)(m0 + wr + i * 16 + lg * 4 + r) * N + n0 + wc + j * 16 + li] =
            acc[i][j][r];
}

// ---------------- fused RMSNorm + RoPE + gain + scale ----------------
__global__ __launch_bounds__(256) void rmsrope(const float* __restrict__ in, int ld,
                                               int nh, const float* __restrict__ gain,
                                               u16* __restrict__ out, int S,
                                               const float2* __restrict__ tbl,
                                               float scale) {
  const int w = threadIdx.x >> 6;
  const int t = threadIdx.x & 63;
  const int row = blockIdx.x * 4 + w;
  const int h = blockIdx.y;
  const float v = in[(size_t)row * ld + h * 64 + t];
  float ss = v * v;
#pragma unroll
  for (int m = 1; m < 64; m <<= 1) ss += __shfl_xor(ss, m);
  const float vn = v * rsqrtf(ss * (1.0f / 64.0f) + 1.1920929e-07f);
  const float partner = __shfl_xor(vn, 32);
  const int b = row / S;
  const int s = row - b * S;
  const float2 cs2 = tbl[s * 32 + (t & 31)];
  float o = (t < 32) ? (vn * cs2.x + partner * cs2.y)
                     : (vn * cs2.x - partner * cs2.y);
  o *= scale;
  if (gain) o *= gain[h];
  out[((size_t)(b * nh + h) * S + s) * 64 + t] = f2bf(o);
}

// ---------------- V cast+transpose via LDS: qf cols 1280.. -> [B][4][64][S] --
// grid: b*32 + kv*8 + sc ; 256-row s-chunks
__global__ __launch_bounds__(256) void vcast2(const float* __restrict__ qf,
                                              u16* __restrict__ vt, int S) {
  const int blk = blockIdx.x;
  const int sc = blk & 7;
  const int kv = (blk >> 3) & 3;
  const int b = blk >> 5;
  __shared__ u16 T[256][66];
  const int tid = threadIdx.x;
  const int dcol = tid & 63;
  const int w = tid >> 6;
  const float* src =
      qf + (size_t)(b * S + sc * 256) * 1536 + 1280 + kv * 64 + dcol;
#pragma unroll 4
  for (int i = 0; i < 64; ++i) {
    const int sl = i * 4 + w;
    T[sl][dcol] = f2bf(src[(size_t)sl * 1536]);
  }
  __syncthreads();
  u16* dst = vt + (size_t)((b * 4 + kv) * 64) * S + sc * 256;
  const int l = tid & 63;
#pragma unroll 4
  for (int i = 0; i < 16; ++i) {
    const int drow = i * 4 + w;
    u16x4 v4;
    v4[0] = T[l * 4 + 0][drow];
    v4[1] = T[l * 4 + 1][drow];
    v4[2] = T[l * 4 + 2][drow];
    v4[3] = T[l * 4 + 3][drow];
    *(u16x4*)(dst + (size_t)drow * S + l * 4) = v4;
  }
}

// ---------------- flash attention v6: uniform 33-iter blocks ----------------
// qh pre-scaled by 0.125*log2(e) -> scores in log2 domain, exp2 softmax.
// grid 512: bh = blockIdx&31, d = blockIdx>>5; block does q-tiles {d, 31-d}.
__global__ __launch_bounds__(256) void attn6(const u16* __restrict__ qh,
                                             const u16* __restrict__ kh,
                                             const u16* __restrict__ vt,
                                             u16* __restrict__ y, int S) {
  const int bh = blockIdx.x & 31;
  const int dd = blockIdx.x >> 5;  // 0..15
  const int h = bh & 15, b = bh >> 4;
  const int kvh = h >> 2;
  const int tid = threadIdx.x;
  const int wave = tid >> 6;
  const int lane = tid & 63;
  const int lg = lane >> 4, li = lane & 15;

  const u16* kp = kh + (size_t)(b * 4 + kvh) * S * 64;
  const u16* vp = vt + (size_t)(b * 4 + kvh) * 64 * S;

  __shared__ __align__(16) u16 Ks[2][64][64];
  __shared__ __align__(16) u16 Vs[2][64][64];
  __shared__ __align__(16) u16 Ps[4][16][64];

  const int s_r0 = tid >> 3;
  const int s_c = (tid & 7) ^ ((tid >> 3) & 7);
  char* psrow = (char*)&Ps[wave][li][0];
  const int swz = li & 7;
  const int rdsw = li & 7;
  const f32x4 fz = {0.f, 0.f, 0.f, 0.f};
  const u16x8 ones_u = {0x3F80, 0x3F80, 0x3F80, 0x3F80,
                        0x3F80, 0x3F80, 0x3F80, 0x3F80};
  const bf16x8 onesb = *(const bf16x8*)&ones_u;

#define STAGE(buf, kb)                                                        \
  {                                                                           \
    const u16* gk = kp + (size_t)((kb) + s_r0) * 64 + s_c * 8;                \
    gl2lds16(gk, &Ks[buf][0][0] + (size_t)tid * 8);                           \
    gl2lds16(gk + (size_t)32 * 64, &Ks[buf][32][0] + (size_t)tid * 8);        \
    const u16* gv = vp + (size_t)s_r0 * S + (kb) + s_c * 8;                   \
    gl2lds16(gv, &Vs[buf][0][0] + (size_t)tid * 8);                           \
    gl2lds16(gv + (size_t)32 * S, &Vs[buf][32][0] + (size_t)tid * 8);         \
  }

  for (int p = 0; p < 2; ++p) {
    const int qb = p ? 31 - dd : dd;
    const int q0 = qb * 64 + wave * 16;
    const int qrow = q0 + li;
    const u16* qp = qh + ((size_t)(b * 16 + h) * S + q0) * 64;

    STAGE(0, 0)
    const bf16x8 qf0 = *(const bf16x8*)&qp[li * 64 + lg * 8];
    const bf16x8 qf1 = *(const bf16x8*)&qp[li * 64 + 32 + lg * 8];

    f32x4 o[4];
#pragma unroll
    for (int j = 0; j < 4; j++) o[j] = fz;
    f32x4 lsum = fz;
    float mrow = -1e30f;

    int buf = 0;
    for (int tt = 0; tt <= qb; ++tt) {
      if (tt < qb) {
        STAGE(buf ^ 1, (tt + 1) * 64)
        asm volatile("s_waitcnt vmcnt(4)" ::: "memory");
      } else {
        asm volatile("s_waitcnt vmcnt(0)" ::: "memory");
      }
      __builtin_amdgcn_s_barrier();
      const int kb = tt * 64;
      f32x4 s[4];
      __builtin_amdgcn_s_setprio(1);
#pragma unroll
      for (int t = 0; t < 4; t++) {
        const bf16x8 ka =
            *(const bf16x8*)&Ks[buf][t * 16 + li][((lg) ^ rdsw) * 8];
        const bf16x8 kc =
            *(const bf16x8*)&Ks[buf][t * 16 + li][((lg + 4) ^ rdsw) * 8];
        s[t] = mfma16(ka, qf0, fz);
        s[t] = mfma16(kc, qf1, s[t]);
      }
      __builtin_amdgcn_s_setprio(0);
      float pv[16];
      if (tt < qb) {
#pragma unroll
        for (int t = 0; t < 4; t++)
#pragma unroll
          for (int r = 0; r < 4; r++) pv[t * 4 + r] = s[t][r];
      } else {
#pragma unroll
        for (int t = 0; t < 4; t++)
#pragma unroll
          for (int r = 0; r < 4; r++)
            pv[t * 4 + r] =
                (kb + t * 16 + lg * 4 + r > qrow) ? -1e30f : s[t][r];
      }
      // max via v_max3 chains
      const float a0 = fmaxf(fmaxf(pv[0], pv[1]), pv[2]);
      const float a1 = fmaxf(fmaxf(pv[3], pv[4]), pv[5]);
      const float a2 = fmaxf(fmaxf(pv[6], pv[7]), pv[8]);
      const float a3 = fmaxf(fmaxf(pv[9], pv[10]), pv[11]);
      const float a4 = fmaxf(fmaxf(pv[12], pv[13]), pv[14]);
      float mt = fmaxf(fmaxf(fmaxf(a0, a1), a2), fmaxf(fmaxf(a3, a4), pv[15]));
      mt = fmaxf(mt, __shfl_xor(mt, 16));
      mt = fmaxf(mt, __shfl_xor(mt, 32));
      // defer-max (log2 domain, THR=8 -> P bounded by 256)
      if (!__all(mt <= mrow + 8.f)) {
        const float mnew = fmaxf(mrow, mt);
        const float corr = exp2f(mrow - mnew);
        mrow = mnew;
#pragma unroll
        for (int r = 0; r < 4; r++) {
          const float cb = __shfl(corr, lg * 4 + r);
          o[0][r] *= cb; o[1][r] *= cb; o[2][r] *= cb; o[3][r] *= cb;
          lsum[r] *= cb;
        }
      }
#pragma unroll
      for (int i = 0; i < 16; i++) pv[i] = exp2f(pv[i] - mrow);
      // P -> LDS (packed bf16, swizzled 8B blocks)
#pragma unroll
      for (int t = 0; t < 4; t++) {
        uint2 w;
        w.x = cvtpk(pv[t * 4 + 0], pv[t * 4 + 1]);
        w.y = cvtpk(pv[t * 4 + 2], pv[t * 4 + 3]);
        const int c8 = (t * 4 + lg) ^ (swz << 1);
        *(uint2*)(psrow + c8 * 8) = w;
      }
      const bf16x8 pa0 = *(const bf16x8*)(psrow + ((lg + 0) ^ swz) * 16);
      const bf16x8 pa1 = *(const bf16x8*)(psrow + ((lg + 4) ^ swz) * 16);
      __builtin_amdgcn_s_setprio(1);
#pragma unroll
      for (int j = 0; j < 4; j++) {
        const bf16x8 v0 =
            *(const bf16x8*)&Vs[buf][j * 16 + li][((lg) ^ rdsw) * 8];
        const bf16x8 v1 =
            *(const bf16x8*)&Vs[buf][j * 16 + li][((lg + 4) ^ rdsw) * 8];
        o[j] = mfma16(pa0, v0, o[j]);
        o[j] = mfma16(pa1, v1, o[j]);
      }
      // row-sums on the matrix pipe (replaces psum adds + shuffles)
      lsum = mfma16(pa0, onesb, lsum);
      lsum = mfma16(pa1, onesb, lsum);
      __builtin_amdgcn_s_setprio(0);
      __builtin_amdgcn_s_barrier();
      buf ^= 1;
    }
    // epilogue: lsum already in o[] row layout (row = q0 + lg*4 + r)
#pragma unroll
    for (int j = 0; j < 4; j++)
#pragma unroll
      for (int r = 0; r < 4; r++)
        y[((size_t)(b * S + q0 + lg * 4 + r)) * 1024 + h * 64 + j * 16 + li] =
            f2bf(o[j][r] / lsum[r]);
  }
#undef STAGE
}

extern "C" void kernel_launch(void* const* d_in, const int* in_sizes, int n_in,
                              void* d_out, int out_size, void* d_ws, size_t ws_size,
                              hipStream_t stream) {
  const float* x  = (const float*)d_in[0];
  const float* Wq = (const float*)d_in[1];
  const float* Wk = (const float*)d_in[2];
  const float* Wv = (const float*)d_in[3];
  const float* Wp = (const float*)d_in[4];
  const float* qg = (const float*)d_in[5];
  float* out = (float*)d_out;

  const int S = 2048;
  char* ws = (char*)d_ws;
  u16*   xb   = (u16*)(ws + 0);            // 8 MB
  u16*   wallb= (u16*)(ws + 8388608);      // [Wq;Wk;Wv] bf16 (3 MB)
  u16*   wpb  = (u16*)(ws + 11534336);     // 2 MB
  float* qf   = (float*)(ws + 13631488);   // [4096][1536] f32 (24 MB)
  u16*   qhb  = (u16*)(ws + 38797312);     // 8 MB
  u16*   khb  = (u16*)(ws + 47185920);     // 2 MB
  u16*   vtb  = (u16*)(ws + 49283072);     // 2 MB
  u16*   yb   = (u16*)(ws + 51380224);     // 8 MB
  float2* tbl = (float2*)(ws + 8388608);   // reuses dead QKV-weight region
  if (ws_size < 59768832) return;

  castf2b<<<2048, 256, 0, stream>>>(x, xb, 4194304);
  castf2b<<<512, 256, 0, stream>>>(Wq, wallb, 1048576);
  castf2b<<<128, 256, 0, stream>>>(Wk, wallb + 1048576, 262144);
  castf2b<<<128, 256, 0, stream>>>(Wv, wallb + 1310720, 262144);
  castf2b<<<512, 256, 0, stream>>>(Wp, wpb, 1048576);

  gemm_bt<<<dim3(12, 32), 256, 0, stream>>>(xb, wallb, qf, 4096, 1536, 1024);

  trigtab<<<256, 256, 0, stream>>>(tbl, S);

  // q pre-scaled by 0.125 * log2(e) -> attention works in exp2 domain
  rmsrope<<<dim3(1024, 16), 256, 0, stream>>>(qf, 1536, 16, qg, qhb, S, tbl,
                                              0.18033688011112042f);
  rmsrope<<<dim3(1024, 4), 256, 0, stream>>>(qf + 1024, 1536, 4, nullptr, khb,
                                             S, tbl, 1.0f);
  vcast2<<<64, 256, 0, stream>>>(qf, vtb, S);

  attn6<<<512, 256, 0, stream>>>(qhb, khb, vtb, yb, S);

  gemm_bt<<<dim3(8, 32), 256, 0, stream>>>(yb, wpb, out, 4096, 1024, 1024);
}

// Round 8
// 127.129 us; speedup vs baseline: 2.9464x; 1.0898x over previous
//
#include <hip/hip_runtime.h>

typedef unsigned short u16;
typedef __bf16 bf16_t;
typedef bf16_t bf16x8 __attribute__((ext_vector_type(8)));
typedef float f32x4 __attribute__((ext_vector_type(4)));
typedef u16 u16x8 __attribute__((ext_vector_type(8)));
typedef u16 u16x4 __attribute__((ext_vector_type(4)));

__device__ __forceinline__ u16 f2bf(float f) {
  unsigned u = __float_as_uint(f);
  u += 0x7fffu + ((u >> 16) & 1u);
  return (u16)(u >> 16);
}

__device__ __forceinline__ unsigned cvtpk(float lo, float hi) {
  unsigned r;
  asm("v_cvt_pk_bf16_f32 %0, %1, %2" : "=v"(r) : "v"(lo), "v"(hi));
  return r;
}

__device__ __forceinline__ f32x4 mfma16(bf16x8 a, bf16x8 b, f32x4 c) {
  return __builtin_amdgcn_mfma_f32_16x16x32_bf16(a, b, c, 0, 0, 0);
}

__device__ __forceinline__ void gl2lds16(const u16* g, u16* l) {
  __builtin_amdgcn_global_load_lds(
      (__attribute__((address_space(1))) void*)(u16*)g,
      (__attribute__((address_space(3))) void*)l, 16, 0, 0);
}

// ---------------- fp32 -> bf16 cast, 8 elems/thread ----------------
__global__ __launch_bounds__(256) void castf2b(const float* __restrict__ in,
                                               u16* __restrict__ out, int n) {
  int i = (blockIdx.x * 256 + threadIdx.x) * 8;
  if (i < n) {
    float4 a = *(const float4*)&in[i];
    float4 b = *(const float4*)&in[i + 4];
    uint4 o;
    o.x = cvtpk(a.x, a.y);
    o.y = cvtpk(a.z, a.w);
    o.z = cvtpk(b.x, b.y);
    o.w = cvtpk(b.z, b.w);
    *(uint4*)&out[i] = o;
  }
}

// ---------------- cos/sin table ----------------
__global__ __launch_bounds__(256) void trigtab(float2* __restrict__ tbl, int S) {
  int idx = blockIdx.x * 256 + threadIdx.x;
  if (idx < S * 32) {
    int s = idx >> 5, i = idx & 31;
    float inv = exp2f(-(float)i * (13.287712379549449f / 32.0f));
    float fr = (float)s * inv;
    float sn, cs;
    sincosf(fr, &sn, &cs);
    tbl[idx] = make_float2(cs, sn);
  }
}

// ---------------- GEMM v3: C[M][N] = A[M][K] * B[N][K]^T, tiled BMxBN -------
// 4 waves in 2x2; wave covers (BM/2)x(BN/2). Requires BM,BN multiples of 32.
template <int BM, int BN>
__global__ __launch_bounds__(256) void gemm_bt(const u16* __restrict__ A,
                                               const u16* __restrict__ B,
                                               float* __restrict__ C,
                                               int M, int N, int K) {
  constexpr int FM = BM / 32;        // row frags per wave
  constexpr int FN = BN / 32;        // col frags per wave
  constexpr int NL = (BM + BN) / 32; // staging loads per tile
  __shared__ __align__(16) u16 As[2][BM][64];
  __shared__ __align__(16) u16 Bs[2][BN][64];
  const int tid = threadIdx.x;
  const int lane = tid & 63;
  const int lg = lane >> 4, li = lane & 15;
  const int wave = tid >> 6;
  const int wr = (wave >> 1) * (BM / 2), wc = (wave & 1) * (BN / 2);
  const int m0 = blockIdx.y * BM, n0 = blockIdx.x * BN;

  const int s_r = tid >> 3;
  const int s_c = (tid & 7) ^ ((tid >> 3) & 7);
  const int rdsw = li & 7;

  auto GSTAGE = [&](int buf, int k0) {
    const u16* ga = &A[(size_t)(m0 + s_r) * K + k0 + s_c * 8];
#pragma unroll
    for (int i = 0; i < BM / 32; i++)
      gl2lds16(ga + (size_t)(i * 32) * K, &As[buf][i * 32][0] + (size_t)tid * 8);
    const u16* gb = &B[(size_t)(n0 + s_r) * K + k0 + s_c * 8];
#pragma unroll
    for (int i = 0; i < BN / 32; i++)
      gl2lds16(gb + (size_t)(i * 32) * K, &Bs[buf][i * 32][0] + (size_t)tid * 8);
  };

  const f32x4 fz = {0.f, 0.f, 0.f, 0.f};
  f32x4 acc[FM][FN];
#pragma unroll
  for (int i = 0; i < FM; i++)
#pragma unroll
    for (int j = 0; j < FN; j++) acc[i][j] = fz;

  GSTAGE(0, 0);
  int buf = 0;
  const int nk = K >> 6;
  for (int t = 0; t < nk; ++t) {
    if (t + 1 < nk) {
      GSTAGE(buf ^ 1, (t + 1) * 64);
      if constexpr (NL == 6)
        asm volatile("s_waitcnt vmcnt(6)" ::: "memory");
      else if constexpr (NL == 7)
        asm volatile("s_waitcnt vmcnt(7)" ::: "memory");
      else
        asm volatile("s_waitcnt vmcnt(8)" ::: "memory");
    } else {
      asm volatile("s_waitcnt vmcnt(0)" ::: "memory");
    }
    __builtin_amdgcn_s_barrier();
#pragma unroll
    for (int kk = 0; kk < 2; kk++) {
      bf16x8 af[FM], bfr[FN];
#pragma unroll
      for (int i = 0; i < FM; i++)
        af[i] = *(const bf16x8*)&As[buf][wr + i * 16 + li]
                                   [((kk * 4 + lg) ^ rdsw) * 8];
#pragma unroll
      for (int j = 0; j < FN; j++)
        bfr[j] = *(const bf16x8*)&Bs[buf][wc + j * 16 + li]
                                    [((kk * 4 + lg) ^ rdsw) * 8];
      __builtin_amdgcn_s_setprio(1);
#pragma unroll
      for (int i = 0; i < FM; i++)
#pragma unroll
        for (int j = 0; j < FN; j++) acc[i][j] = mfma16(af[i], bfr[j], acc[i][j]);
      __builtin_amdgcn_s_setprio(0);
    }
    __builtin_amdgcn_s_barrier();
    buf ^= 1;
  }
#pragma unroll
  for (int i = 0; i < FM; i++)
#pragma unroll
    for (int j = 0; j < FN; j++)
#pragma unroll
      for (int r = 0; r < 4; r++)
        C[(size_t)(m0 + wr + i * 16 + lg * 4 + r) * N + n0 + wc + j * 16 + li] =
            acc[i][j][r];
}

// ---------------- fused RMSNorm + RoPE + gain + scale ----------------
__global__ __launch_bounds__(256) void rmsrope(const float* __restrict__ in, int ld,
                                               int nh, const float* __restrict__ gain,
                                               u16* __restrict__ out, int S,
                                               const float2* __restrict__ tbl,
                                               float scale) {
  const int w = threadIdx.x >> 6;
  const int t = threadIdx.x & 63;
  const int row = blockIdx.x * 4 + w;
  const int h = blockIdx.y;
  const float v = in[(size_t)row * ld + h * 64 + t];
  float ss = v * v;
#pragma unroll
  for (int m = 1; m < 64; m <<= 1) ss += __shfl_xor(ss, m);
  const float vn = v * rsqrtf(ss * (1.0f / 64.0f) + 1.1920929e-07f);
  const float partner = __shfl_xor(vn, 32);
  const int b = row / S;
  const int s = row - b * S;
  const float2 cs2 = tbl[s * 32 + (t & 31)];
  float o = (t < 32) ? (vn * cs2.x + partner * cs2.y)
                     : (vn * cs2.x - partner * cs2.y);
  o *= scale;
  if (gain) o *= gain[h];
  out[((size_t)(b * nh + h) * S + s) * 64 + t] = f2bf(o);
}

// ---------------- V cast+transpose via LDS ----------------
__global__ __launch_bounds__(256) void vcast2(const float* __restrict__ qf,
                                              u16* __restrict__ vt, int S) {
  const int blk = blockIdx.x;
  const int sc = blk & 7;
  const int kv = (blk >> 3) & 3;
  const int b = blk >> 5;
  __shared__ u16 T[256][66];
  const int tid = threadIdx.x;
  const int dcol = tid & 63;
  const int w = tid >> 6;
  const float* src =
      qf + (size_t)(b * S + sc * 256) * 1536 + 1280 + kv * 64 + dcol;
#pragma unroll 4
  for (int i = 0; i < 64; ++i) {
    const int sl = i * 4 + w;
    T[sl][dcol] = f2bf(src[(size_t)sl * 1536]);
  }
  __syncthreads();
  u16* dst = vt + (size_t)((b * 4 + kv) * 64) * S + sc * 256;
  const int l = tid & 63;
#pragma unroll 4
  for (int i = 0; i < 16; ++i) {
    const int drow = i * 4 + w;
    u16x4 v4;
    v4[0] = T[l * 4 + 0][drow];
    v4[1] = T[l * 4 + 1][drow];
    v4[2] = T[l * 4 + 2][drow];
    v4[3] = T[l * 4 + 3][drow];
    *(u16x4*)(dst + (size_t)drow * S + l * 4) = v4;
  }
}

// ---------------- flash attention v7: 4 blocks/CU, balanced qb sets ---------
// qh pre-scaled by 0.125*log2(e). grid 1024: bh = idx&31, g = idx>>5;
// same-CU sets {31-d, 16+d, 15-d, d} sum to 66 iters; heavy blocks dispatch first.
__global__ __launch_bounds__(256) void attn7(const u16* __restrict__ qh,
                                             const u16* __restrict__ kh,
                                             const u16* __restrict__ vt,
                                             u16* __restrict__ y, int S) {
  const int bh = blockIdx.x & 31;
  const int g = blockIdx.x >> 5;
  const int d = g & 7, u = g >> 3;
  const int qb = (u == 0) ? 31 - d : (u == 1) ? 16 + d : (u == 2) ? 15 - d : d;
  const int h = bh & 15, b = bh >> 4;
  const int kvh = h >> 2;
  const int tid = threadIdx.x;
  const int wave = tid >> 6;
  const int lane = tid & 63;
  const int lg = lane >> 4, li = lane & 15;
  const int q0 = qb * 64 + wave * 16;
  const int qrow = q0 + li;

  const u16* qp = qh + ((size_t)(b * 16 + h) * S + q0) * 64;
  const u16* kp = kh + (size_t)(b * 4 + kvh) * S * 64;
  const u16* vp = vt + (size_t)(b * 4 + kvh) * 64 * S;

  __shared__ __align__(16) u16 Ks[2][64][64];
  __shared__ __align__(16) u16 Vs[2][64][64];
  __shared__ __align__(16) u16 Ps[4][16][64];

  const int s_r0 = tid >> 3;
  const int s_c = (tid & 7) ^ ((tid >> 3) & 7);
  char* psrow = (char*)&Ps[wave][li][0];
  const int swz = li & 7;
  const int rdsw = li & 7;
  const f32x4 fz = {0.f, 0.f, 0.f, 0.f};
  const u16x8 ones_u = {0x3F80, 0x3F80, 0x3F80, 0x3F80,
                        0x3F80, 0x3F80, 0x3F80, 0x3F80};
  const bf16x8 onesb = *(const bf16x8*)&ones_u;

#define STAGE(buf, kb)                                                        \
  {                                                                           \
    const u16* gk = kp + (size_t)((kb) + s_r0) * 64 + s_c * 8;                \
    gl2lds16(gk, &Ks[buf][0][0] + (size_t)tid * 8);                           \
    gl2lds16(gk + (size_t)32 * 64, &Ks[buf][32][0] + (size_t)tid * 8);        \
    const u16* gv = vp + (size_t)s_r0 * S + (kb) + s_c * 8;                   \
    gl2lds16(gv, &Vs[buf][0][0] + (size_t)tid * 8);                           \
    gl2lds16(gv + (size_t)32 * S, &Vs[buf][32][0] + (size_t)tid * 8);         \
  }

  STAGE(0, 0)
  const bf16x8 qf0 = *(const bf16x8*)&qp[li * 64 + lg * 8];
  const bf16x8 qf1 = *(const bf16x8*)&qp[li * 64 + 32 + lg * 8];

  f32x4 o[4];
#pragma unroll
  for (int j = 0; j < 4; j++) o[j] = fz;
  f32x4 lsum = fz;
  float mrow = -1e30f;

  int buf = 0;
  for (int tt = 0; tt <= qb; ++tt) {
    if (tt < qb) {
      STAGE(buf ^ 1, (tt + 1) * 64)
      asm volatile("s_waitcnt vmcnt(4)" ::: "memory");
    } else {
      asm volatile("s_waitcnt vmcnt(0)" ::: "memory");
    }
    __builtin_amdgcn_s_barrier();
    const int kb = tt * 64;
    f32x4 s[4];
    __builtin_amdgcn_s_setprio(1);
#pragma unroll
    for (int t = 0; t < 4; t++) {
      const bf16x8 ka =
          *(const bf16x8*)&Ks[buf][t * 16 + li][((lg) ^ rdsw) * 8];
      const bf16x8 kc =
          *(const bf16x8*)&Ks[buf][t * 16 + li][((lg + 4) ^ rdsw) * 8];
      s[t] = mfma16(ka, qf0, fz);
      s[t] = mfma16(kc, qf1, s[t]);
    }
    __builtin_amdgcn_s_setprio(0);
    float pv[16];
    if (tt < qb) {
#pragma unroll
      for (int t = 0; t < 4; t++)
#pragma unroll
        for (int r = 0; r < 4; r++) pv[t * 4 + r] = s[t][r];
    } else {
#pragma unroll
      for (int t = 0; t < 4; t++)
#pragma unroll
        for (int r = 0; r < 4; r++)
          pv[t * 4 + r] =
              (kb + t * 16 + lg * 4 + r > qrow) ? -1e30f : s[t][r];
    }
    const float a0 = fmaxf(fmaxf(pv[0], pv[1]), pv[2]);
    const float a1 = fmaxf(fmaxf(pv[3], pv[4]), pv[5]);
    const float a2 = fmaxf(fmaxf(pv[6], pv[7]), pv[8]);
    const float a3 = fmaxf(fmaxf(pv[9], pv[10]), pv[11]);
    const float a4 = fmaxf(fmaxf(pv[12], pv[13]), pv[14]);
    float mt = fmaxf(fmaxf(fmaxf(a0, a1), a2), fmaxf(fmaxf(a3, a4), pv[15]));
    mt = fmaxf(mt, __shfl_xor(mt, 16));
    mt = fmaxf(mt, __shfl_xor(mt, 32));
    if (!__all(mt <= mrow + 8.f)) {
      const float mnew = fmaxf(mrow, mt);
      const float corr = exp2f(mrow - mnew);
      mrow = mnew;
#pragma unroll
      for (int r = 0; r < 4; r++) {
        const float cb = __shfl(corr, lg * 4 + r);
        o[0][r] *= cb; o[1][r] *= cb; o[2][r] *= cb; o[3][r] *= cb;
        lsum[r] *= cb;
      }
    }
#pragma unroll
    for (int i = 0; i < 16; i++) pv[i] = exp2f(pv[i] - mrow);
#pragma unroll
    for (int t = 0; t < 4; t++) {
      uint2 w;
      w.x = cvtpk(pv[t * 4 + 0], pv[t * 4 + 1]);
      w.y = cvtpk(pv[t * 4 + 2], pv[t * 4 + 3]);
      const int c8 = (t * 4 + lg) ^ (swz << 1);
      *(uint2*)(psrow + c8 * 8) = w;
    }
    const bf16x8 pa0 = *(const bf16x8*)(psrow + ((lg + 0) ^ swz) * 16);
    const bf16x8 pa1 = *(const bf16x8*)(psrow + ((lg + 4) ^ swz) * 16);
    __builtin_amdgcn_s_setprio(1);
#pragma unroll
    for (int j = 0; j < 4; j++) {
      const bf16x8 v0 =
          *(const bf16x8*)&Vs[buf][j * 16 + li][((lg) ^ rdsw) * 8];
      const bf16x8 v1 =
          *(const bf16x8*)&Vs[buf][j * 16 + li][((lg + 4) ^ rdsw) * 8];
      o[j] = mfma16(pa0, v0, o[j]);
      o[j] = mfma16(pa1, v1, o[j]);
    }
    lsum = mfma16(pa0, onesb, lsum);
    lsum = mfma16(pa1, onesb, lsum);
    __builtin_amdgcn_s_setprio(0);
    __builtin_amdgcn_s_barrier();
    buf ^= 1;
  }
#undef STAGE
#pragma unroll
  for (int j = 0; j < 4; j++)
#pragma unroll
    for (int r = 0; r < 4; r++)
      y[((size_t)(b * S + q0 + lg * 4 + r)) * 1024 + h * 64 + j * 16 + li] =
          f2bf(o[j][r] / lsum[r]);
}

extern "C" void kernel_launch(void* const* d_in, const int* in_sizes, int n_in,
                              void* d_out, int out_size, void* d_ws, size_t ws_size,
                              hipStream_t stream) {
  const float* x  = (const float*)d_in[0];
  const float* Wq = (const float*)d_in[1];
  const float* Wk = (const float*)d_in[2];
  const float* Wv = (const float*)d_in[3];
  const float* Wp = (const float*)d_in[4];
  const float* qg = (const float*)d_in[5];
  float* out = (float*)d_out;

  const int S = 2048;
  char* ws = (char*)d_ws;
  u16*   xb   = (u16*)(ws + 0);            // 8 MB
  u16*   wallb= (u16*)(ws + 8388608);      // [Wq;Wk;Wv] bf16 (3 MB)
  u16*   wpb  = (u16*)(ws + 11534336);     // 2 MB
  float* qf   = (float*)(ws + 13631488);   // [4096][1536] f32 (24 MB)
  u16*   qhb  = (u16*)(ws + 38797312);     // 8 MB
  u16*   khb  = (u16*)(ws + 47185920);     // 2 MB
  u16*   vtb  = (u16*)(ws + 49283072);     // 2 MB
  u16*   yb   = (u16*)(ws + 51380224);     // 8 MB
  float2* tbl = (float2*)(ws + 8388608);   // reuses dead QKV-weight region
  if (ws_size < 59768832) return;

  castf2b<<<2048, 256, 0, stream>>>(x, xb, 4194304);
  castf2b<<<512, 256, 0, stream>>>(Wq, wallb, 1048576);
  castf2b<<<128, 256, 0, stream>>>(Wk, wallb + 1048576, 262144);
  castf2b<<<128, 256, 0, stream>>>(Wv, wallb + 1310720, 262144);
  castf2b<<<512, 256, 0, stream>>>(Wp, wpb, 1048576);

  // fused QKV projection: 128x96 tile -> 512 blocks = exactly 2/CU
  gemm_bt<128, 96><<<dim3(16, 32), 256, 0, stream>>>(xb, wallb, qf, 4096, 1536, 1024);

  trigtab<<<256, 256, 0, stream>>>(tbl, S);

  rmsrope<<<dim3(1024, 16), 256, 0, stream>>>(qf, 1536, 16, qg, qhb, S, tbl,
                                              0.18033688011112042f);
  rmsrope<<<dim3(1024, 4), 256, 0, stream>>>(qf + 1024, 1536, 4, nullptr, khb,
                                             S, tbl, 1.0f);
  vcast2<<<64, 256, 0, stream>>>(qf, vtb, S);

  attn7<<<1024, 256, 0, stream>>>(qhb, khb, vtb, yb, S);

  // output projection: 64x128 tile -> 512 blocks = exactly 2/CU
  gemm_bt<64, 128><<<dim3(8, 64), 256, 0, stream>>>(yb, wpb, out, 4096, 1024, 1024);
}

// Round 9
// 106.982 us; speedup vs baseline: 3.5013x; 1.1883x over previous
//
#include <hip/hip_runtime.h>

typedef unsigned short u16;
typedef __bf16 bf16_t;
typedef bf16_t bf16x8 __attribute__((ext_vector_type(8)));
typedef float f32x4 __attribute__((ext_vector_type(4)));
typedef u16 u16x8 __attribute__((ext_vector_type(8)));
typedef u16 u16x4 __attribute__((ext_vector_type(4)));

__device__ __forceinline__ u16 f2bf(float f) {
  unsigned u = __float_as_uint(f);
  u += 0x7fffu + ((u >> 16) & 1u);
  return (u16)(u >> 16);
}

__device__ __forceinline__ float bf2f(u16 u) {
  return __uint_as_float((unsigned)u << 16);
}

__device__ __forceinline__ unsigned cvtpk(float lo, float hi) {
  unsigned r;
  asm("v_cvt_pk_bf16_f32 %0, %1, %2" : "=v"(r) : "v"(lo), "v"(hi));
  return r;
}

__device__ __forceinline__ f32x4 mfma16(bf16x8 a, bf16x8 b, f32x4 c) {
  return __builtin_amdgcn_mfma_f32_16x16x32_bf16(a, b, c, 0, 0, 0);
}

__device__ __forceinline__ void gl2lds16(const u16* g, u16* l) {
  __builtin_amdgcn_global_load_lds(
      (__attribute__((address_space(1))) void*)(u16*)g,
      (__attribute__((address_space(3))) void*)l, 16, 0, 0);
}

__device__ __forceinline__ void cast8(const float* __restrict__ in,
                                      u16* __restrict__ out, int i) {
  float4 a = *(const float4*)&in[i];
  float4 b = *(const float4*)&in[i + 4];
  uint4 o;
  o.x = cvtpk(a.x, a.y);
  o.y = cvtpk(a.z, a.w);
  o.z = cvtpk(b.x, b.y);
  o.w = cvtpk(b.z, b.w);
  *(uint4*)&out[i] = o;
}

// ---------------- megacast: all f32->bf16 casts + trig table, one launch ----
__global__ __launch_bounds__(256) void megacast(
    const float* __restrict__ x, const float* __restrict__ Wq,
    const float* __restrict__ Wk, const float* __restrict__ Wv,
    const float* __restrict__ Wp, u16* __restrict__ xb,
    u16* __restrict__ wallb, u16* __restrict__ wpb,
    float2* __restrict__ tbl) {
  const int blk = blockIdx.x;
  const int tid = threadIdx.x;
  if (blk < 2048) {
    cast8(x, xb, (blk * 256 + tid) * 8);
  } else if (blk < 2560) {
    cast8(Wq, wallb, ((blk - 2048) * 256 + tid) * 8);
  } else if (blk < 2688) {
    cast8(Wk, wallb + 1048576, ((blk - 2560) * 256 + tid) * 8);
  } else if (blk < 2816) {
    cast8(Wv, wallb + 1310720, ((blk - 2688) * 256 + tid) * 8);
  } else if (blk < 3328) {
    cast8(Wp, wpb, ((blk - 2816) * 256 + tid) * 8);
  } else {
    const int idx = (blk - 3328) * 256 + tid;  // < 65536
    const int s = idx >> 5, i = idx & 31;
    float inv = exp2f(-(float)i * (13.287712379549449f / 32.0f));
    float fr = (float)s * inv;
    float sn, cs;
    sincosf(fr, &sn, &cs);
    tbl[idx] = make_float2(cs, sn);
  }
}

// ---------------- GEMM: C[M][N] = A[M][K] * B[N][K]^T, tiled BMxBN ----------
template <int BM, int BN, bool O16>
__global__ __launch_bounds__(256) void gemm_bt(const u16* __restrict__ A,
                                               const u16* __restrict__ B,
                                               void* __restrict__ Cv,
                                               int M, int N, int K) {
  constexpr int FM = BM / 32;
  constexpr int FN = BN / 32;
  constexpr int NL = (BM + BN) / 32;
  __shared__ __align__(16) u16 As[2][BM][64];
  __shared__ __align__(16) u16 Bs[2][BN][64];
  const int tid = threadIdx.x;
  const int lane = tid & 63;
  const int lg = lane >> 4, li = lane & 15;
  const int wave = tid >> 6;
  const int wr = (wave >> 1) * (BM / 2), wc = (wave & 1) * (BN / 2);
  const int m0 = blockIdx.y * BM, n0 = blockIdx.x * BN;

  const int s_r = tid >> 3;
  const int s_c = (tid & 7) ^ ((tid >> 3) & 7);
  const int rdsw = li & 7;

  auto GSTAGE = [&](int buf, int k0) {
    const u16* ga = &A[(size_t)(m0 + s_r) * K + k0 + s_c * 8];
#pragma unroll
    for (int i = 0; i < BM / 32; i++)
      gl2lds16(ga + (size_t)(i * 32) * K, &As[buf][i * 32][0] + (size_t)tid * 8);
    const u16* gb = &B[(size_t)(n0 + s_r) * K + k0 + s_c * 8];
#pragma unroll
    for (int i = 0; i < BN / 32; i++)
      gl2lds16(gb + (size_t)(i * 32) * K, &Bs[buf][i * 32][0] + (size_t)tid * 8);
  };

  const f32x4 fz = {0.f, 0.f, 0.f, 0.f};
  f32x4 acc[FM][FN];
#pragma unroll
  for (int i = 0; i < FM; i++)
#pragma unroll
    for (int j = 0; j < FN; j++) acc[i][j] = fz;

  GSTAGE(0, 0);
  int buf = 0;
  const int nk = K >> 6;
  for (int t = 0; t < nk; ++t) {
    if (t + 1 < nk) {
      GSTAGE(buf ^ 1, (t + 1) * 64);
      if constexpr (NL == 6)
        asm volatile("s_waitcnt vmcnt(6)" ::: "memory");
      else if constexpr (NL == 7)
        asm volatile("s_waitcnt vmcnt(7)" ::: "memory");
      else
        asm volatile("s_waitcnt vmcnt(8)" ::: "memory");
    } else {
      asm volatile("s_waitcnt vmcnt(0)" ::: "memory");
    }
    __builtin_amdgcn_s_barrier();
#pragma unroll
    for (int kk = 0; kk < 2; kk++) {
      bf16x8 af[FM], bfr[FN];
#pragma unroll
      for (int i = 0; i < FM; i++)
        af[i] = *(const bf16x8*)&As[buf][wr + i * 16 + li]
                                   [((kk * 4 + lg) ^ rdsw) * 8];
#pragma unroll
      for (int j = 0; j < FN; j++)
        bfr[j] = *(const bf16x8*)&Bs[buf][wc + j * 16 + li]
                                    [((kk * 4 + lg) ^ rdsw) * 8];
      __builtin_amdgcn_s_setprio(1);
#pragma unroll
      for (int i = 0; i < FM; i++)
#pragma unroll
        for (int j = 0; j < FN; j++) acc[i][j] = mfma16(af[i], bfr[j], acc[i][j]);
      __builtin_amdgcn_s_setprio(0);
    }
    __builtin_amdgcn_s_barrier();
    buf ^= 1;
  }
#pragma unroll
  for (int i = 0; i < FM; i++)
#pragma unroll
    for (int j = 0; j < FN; j++)
#pragma unroll
      for (int r = 0; r < 4; r++) {
        const size_t idx =
            (size_t)(m0 + wr + i * 16 + lg * 4 + r) * N + n0 + wc + j * 16 + li;
        if constexpr (O16)
          ((u16*)Cv)[idx] = f2bf(acc[i][j][r]);
        else
          ((float*)Cv)[idx] = acc[i][j][r];
      }
}

// ---------------- fused RMSNorm + RoPE for q (20 heads: 16 q + 4 k) ---------
// in: qf bf16 [4096][1536]; q heads scaled by 0.125*log2(e)*gain[h]
__global__ __launch_bounds__(256) void rmsropeqk(const u16* __restrict__ in,
                                                 const float* __restrict__ qg,
                                                 u16* __restrict__ qhb,
                                                 u16* __restrict__ khb, int S,
                                                 const float2* __restrict__ tbl) {
  const int w = threadIdx.x >> 6;
  const int t = threadIdx.x & 63;
  const int row = blockIdx.x * 4 + w;
  const int h = blockIdx.y;  // 0..19
  const bool isq = h < 16;
  const int col = isq ? h * 64 : 1024 + (h - 16) * 64;
  const float v = bf2f(in[(size_t)row * 1536 + col + t]);
  float ss = v * v;
#pragma unroll
  for (int m = 1; m < 64; m <<= 1) ss += __shfl_xor(ss, m);
  const float vn = v * rsqrtf(ss * (1.0f / 64.0f) + 1.1920929e-07f);
  const float partner = __shfl_xor(vn, 32);
  const int b = row / S;
  const int s = row - b * S;
  const float2 cs2 = tbl[s * 32 + (t & 31)];
  float o = (t < 32) ? (vn * cs2.x + partner * cs2.y)
                     : (vn * cs2.x - partner * cs2.y);
  if (isq) {
    o *= 0.18033688011112042f * qg[h];
    qhb[((size_t)(b * 16 + h) * S + s) * 64 + t] = f2bf(o);
  } else {
    khb[((size_t)(b * 4 + (h - 16)) * S + s) * 64 + t] = f2bf(o);
  }
}

// ---------------- V transpose via LDS: qf cols 1280.. -> [B][4][64][S] ------
__global__ __launch_bounds__(256) void vcast2(const u16* __restrict__ qf,
                                              u16* __restrict__ vt, int S) {
  const int blk = blockIdx.x;
  const int sc = blk & 7;
  const int kv = (blk >> 3) & 3;
  const int b = blk >> 5;
  __shared__ u16 T[256][66];
  const int tid = threadIdx.x;
  const int dcol = tid & 63;
  const int w = tid >> 6;
  const u16* src =
      qf + (size_t)(b * S + sc * 256) * 1536 + 1280 + kv * 64 + dcol;
#pragma unroll 4
  for (int i = 0; i < 64; ++i) {
    const int sl = i * 4 + w;
    T[sl][dcol] = src[(size_t)sl * 1536];
  }
  __syncthreads();
  u16* dst = vt + (size_t)((b * 4 + kv) * 64) * S + sc * 256;
  const int l = tid & 63;
#pragma unroll 4
  for (int i = 0; i < 16; ++i) {
    const int drow = i * 4 + w;
    u16x4 v4;
    v4[0] = T[l * 4 + 0][drow];
    v4[1] = T[l * 4 + 1][drow];
    v4[2] = T[l * 4 + 2][drow];
    v4[3] = T[l * 4 + 3][drow];
    *(u16x4*)(dst + (size_t)drow * S + l * 4) = v4;
  }
}

// ---------------- flash attention v8: max-free softmax (a-priori bound) -----
// Scores (log2 domain) provably <= 11.5416*|gain_h| since ||q^||,||k^|| <= 8.
// The bound is folded into the QK^T accumulator init, so softmax is just exp2.
__global__ __launch_bounds__(256) void attn8(const u16* __restrict__ qh,
                                             const u16* __restrict__ kh,
                                             const u16* __restrict__ vt,
                                             const float* __restrict__ qg,
                                             u16* __restrict__ y, int S) {
  const int bh = blockIdx.x & 31;
  const int g = blockIdx.x >> 5;
  const int d = g & 7, u = g >> 3;
  const int qb = (u == 0) ? 31 - d : (u == 1) ? 16 + d : (u == 2) ? 15 - d : d;
  const int h = bh & 15, b = bh >> 4;
  const int kvh = h >> 2;
  const int tid = threadIdx.x;
  const int wave = tid >> 6;
  const int lane = tid & 63;
  const int lg = lane >> 4, li = lane & 15;
  const int q0 = qb * 64 + wave * 16;
  const int qrow = q0 + li;
  const float mrow = 11.541560327111707f * fabsf(qg[h]);

  const u16* qp = qh + ((size_t)(b * 16 + h) * S + q0) * 64;
  const u16* kp = kh + (size_t)(b * 4 + kvh) * S * 64;
  const u16* vp = vt + (size_t)(b * 4 + kvh) * 64 * S;

  __shared__ __align__(16) u16 Ks[2][64][64];
  __shared__ __align__(16) u16 Vs[2][64][64];
  __shared__ __align__(16) u16 Ps[4][16][64];

  const int s_r0 = tid >> 3;
  const int s_c = (tid & 7) ^ ((tid >> 3) & 7);
  char* psrow = (char*)&Ps[wave][li][0];
  const int swz = li & 7;
  const int rdsw = li & 7;
  const f32x4 minit = {-mrow, -mrow, -mrow, -mrow};
  const f32x4 fz = {0.f, 0.f, 0.f, 0.f};
  const u16x8 ones_u = {0x3F80, 0x3F80, 0x3F80, 0x3F80,
                        0x3F80, 0x3F80, 0x3F80, 0x3F80};
  const bf16x8 onesb = *(const bf16x8*)&ones_u;

#define STAGE(buf, kb)                                                        \
  {                                                                           \
    const u16* gk = kp + (size_t)((kb) + s_r0) * 64 + s_c * 8;                \
    gl2lds16(gk, &Ks[buf][0][0] + (size_t)tid * 8);                           \
    gl2lds16(gk + (size_t)32 * 64, &Ks[buf][32][0] + (size_t)tid * 8);        \
    const u16* gv = vp + (size_t)s_r0 * S + (kb) + s_c * 8;                   \
    gl2lds16(gv, &Vs[buf][0][0] + (size_t)tid * 8);                           \
    gl2lds16(gv + (size_t)32 * S, &Vs[buf][32][0] + (size_t)tid * 8);         \
  }

  STAGE(0, 0)
  const bf16x8 qf0 = *(const bf16x8*)&qp[li * 64 + lg * 8];
  const bf16x8 qf1 = *(const bf16x8*)&qp[li * 64 + 32 + lg * 8];

  f32x4 o[4];
#pragma unroll
  for (int j = 0; j < 4; j++) o[j] = fz;
  f32x4 lsum = fz;

  int buf = 0;
  for (int tt = 0; tt <= qb; ++tt) {
    if (tt < qb) {
      STAGE(buf ^ 1, (tt + 1) * 64)
      asm volatile("s_waitcnt vmcnt(4)" ::: "memory");
    } else {
      asm volatile("s_waitcnt vmcnt(0)" ::: "memory");
    }
    __builtin_amdgcn_s_barrier();
    const int kb = tt * 64;
    f32x4 s[4];
    __builtin_amdgcn_s_setprio(1);
#pragma unroll
    for (int t = 0; t < 4; t++) {
      const bf16x8 ka =
          *(const bf16x8*)&Ks[buf][t * 16 + li][((lg) ^ rdsw) * 8];
      const bf16x8 kc =
          *(const bf16x8*)&Ks[buf][t * 16 + li][((lg + 4) ^ rdsw) * 8];
      s[t] = mfma16(ka, qf0, minit);  // accumulator pre-init with -bound
      s[t] = mfma16(kc, qf1, s[t]);
    }
    __builtin_amdgcn_s_setprio(0);
    float pv[16];
    if (tt < qb) {
#pragma unroll
      for (int t = 0; t < 4; t++)
#pragma unroll
        for (int r = 0; r < 4; r++) pv[t * 4 + r] = exp2f(s[t][r]);
    } else {
#pragma unroll
      for (int t = 0; t < 4; t++)
#pragma unroll
        for (int r = 0; r < 4; r++) {
          const float x =
              (kb + t * 16 + lg * 4 + r > qrow) ? -1e30f : s[t][r];
          pv[t * 4 + r] = exp2f(x);
        }
    }
#pragma unroll
    for (int t = 0; t < 4; t++) {
      uint2 w;
      w.x = cvtpk(pv[t * 4 + 0], pv[t * 4 + 1]);
      w.y = cvtpk(pv[t * 4 + 2], pv[t * 4 + 3]);
      const int c8 = (t * 4 + lg) ^ (swz << 1);
      *(uint2*)(psrow + c8 * 8) = w;
    }
    const bf16x8 pa0 = *(const bf16x8*)(psrow + ((lg + 0) ^ swz) * 16);
    const bf16x8 pa1 = *(const bf16x8*)(psrow + ((lg + 4) ^ swz) * 16);
    __builtin_amdgcn_s_setprio(1);
#pragma unroll
    for (int j = 0; j < 4; j++) {
      const bf16x8 v0 =
          *(const bf16x8*)&Vs[buf][j * 16 + li][((lg) ^ rdsw) * 8];
      const bf16x8 v1 =
          *(const bf16x8*)&Vs[buf][j * 16 + li][((lg + 4) ^ rdsw) * 8];
      o[j] = mfma16(pa0, v0, o[j]);
      o[j] = mfma16(pa1, v1, o[j]);
    }
    lsum = mfma16(pa0, onesb, lsum);
    lsum = mfma16(pa1, onesb, lsum);
    __builtin_amdgcn_s_setprio(0);
    __builtin_amdgcn_s_barrier();
    buf ^= 1;
  }
#undef STAGE
#pragma unroll
  for (int j = 0; j < 4; j++)
#pragma unroll
    for (int r = 0; r < 4; r++)
      y[((size_t)(b * S + q0 + lg * 4 + r)) * 1024 + h * 64 + j * 16 + li] =
          f2bf(o[j][r] / lsum[r]);
}

extern "C" void kernel_launch(void* const* d_in, const int* in_sizes, int n_in,
                              void* d_out, int out_size, void* d_ws, size_t ws_size,
                              hipStream_t stream) {
  const float* x  = (const float*)d_in[0];
  const float* Wq = (const float*)d_in[1];
  const float* Wk = (const float*)d_in[2];
  const float* Wv = (const float*)d_in[3];
  const float* Wp = (const float*)d_in[4];
  const float* qg = (const float*)d_in[5];
  float* out = (float*)d_out;

  const int S = 2048;
  char* ws = (char*)d_ws;
  u16*    xb    = (u16*)(ws + 0);          // 8 MB
  u16*    wallb = (u16*)(ws + 8388608);    // 3 MB
  u16*    wpb   = (u16*)(ws + 11534336);   // 2 MB
  float2* tbl   = (float2*)(ws + 13631488);// 512 KB
  u16*    qf    = (u16*)(ws + 14155776);   // [4096][1536] bf16 (12 MB)
  u16*    qhb   = (u16*)(ws + 26738688);   // 8 MB
  u16*    khb   = (u16*)(ws + 35127296);   // 2 MB
  u16*    vtb   = (u16*)(ws + 37224448);   // 2 MB
  u16*    yb    = (u16*)(ws + 39321600);   // 8 MB -> 47710208
  if (ws_size < 47710208) return;

  megacast<<<3584, 256, 0, stream>>>(x, Wq, Wk, Wv, Wp, xb, wallb, wpb, tbl);

  // fused QKV projection, bf16 output: 128x96 tile -> 512 blocks = 2/CU
  gemm_bt<128, 96, true><<<dim3(16, 32), 256, 0, stream>>>(xb, wallb, qf,
                                                           4096, 1536, 1024);

  rmsropeqk<<<dim3(1024, 20), 256, 0, stream>>>(qf, qg, qhb, khb, S, tbl);
  vcast2<<<64, 256, 0, stream>>>(qf, vtb, S);

  attn8<<<1024, 256, 0, stream>>>(qhb, khb, vtb, qg, yb, S);

  // output projection: 64x128 tile -> 512 blocks = 2/CU
  gemm_bt<64, 128, false><<<dim3(8, 64), 256, 0, stream>>>(yb, wpb, out,
                                                           4096, 1024, 1024);
}